// Round 5
// baseline (1264.231 us; speedup 1.0000x reference)
//
#include <hip/hip_runtime.h>

#define NB 8
#define NS 1024
#define ND 768
#define NH 12
#define NHD 64
#define NLAYERS 12
#define NM (NB * NS)   // 8192 rows
#define NQKV3 (3 * ND) // 2304 output cols of fused QKV GEMM
#define QSCALE 0.1803368802f  // (1/8) * log2(e): softmax runs in exp2 domain

typedef _Float16 f16;
typedef _Float16 f16x8 __attribute__((ext_vector_type(8)));
typedef _Float16 f16x4 __attribute__((ext_vector_type(4)));
typedef _Float16 f16x2 __attribute__((ext_vector_type(2)));
typedef float f32x4 __attribute__((ext_vector_type(4)));
typedef float f32x16 __attribute__((ext_vector_type(16)));
typedef unsigned int u32x4 __attribute__((ext_vector_type(4)));

__device__ inline float fexp2(float x) {
  float r;
  asm("v_exp_f32 %0, %1" : "=v"(r) : "v"(x));
  return r;
}

// async global->LDS DMA, 16B per lane; LDS dest = wave-uniform base + lane*16
__device__ __forceinline__ void gload16(const void* g, void* l) {
  __builtin_amdgcn_global_load_lds(
      (const __attribute__((address_space(1))) void*)g,
      (__attribute__((address_space(3))) void*)l, 16, 0, 0);
}

// ---------------------------------------------------------------------------
// One-time weight prep.
//  Wcat[n][d] (f16, B^T layout), n = sel*768 + h*64 + kp:
//    sel 0: Wq[h][d][kp]   sel 1: Wk[h][d][kp]   sel 2: (Wv@Wo)[h][d][kp]
//  bvo[h*64+j] = sum_m bv[h][m]*Wo[h][m][j] + bo[h][j]
//  (softmax rows sum to 1, so ctx@Wo + bo == P@(V@Wo) + bvo — Wo is folded.)
// ---------------------------------------------------------------------------
__global__ __launch_bounds__(256) void prep_weights(
    const float* __restrict__ Wq, const float* __restrict__ Wk,
    const float* __restrict__ Wv, const float* __restrict__ Wo,
    const float* __restrict__ bv, const float* __restrict__ bo,
    f16* __restrict__ Wcat, float* __restrict__ bvo) {
  __shared__ float t0[64][65];
  __shared__ float t1[64 * 64];
  int bid = blockIdx.x, tid = threadIdx.x;
  if (bid < 288) {  // Q,K transposes
    int dt = bid % 12, hh = (bid / 12) % 12, sel = bid / 144;
    const float* W = sel == 0 ? Wq : Wk;
    int d0 = dt * 64;
#pragma unroll
    for (int p = 0; p < 16; ++p) {
      int i = p * 4 + (tid >> 6), kp = tid & 63;
      t0[i][kp] = W[(size_t)(hh * 768 + d0 + i) * 64 + kp];
    }
    __syncthreads();
#pragma unroll
    for (int p = 0; p < 16; ++p) {
      int kp = p * 4 + (tid >> 6), i = tid & 63;
      Wcat[(size_t)(sel * 768 + hh * 64 + kp) * 768 + d0 + i] = (f16)t0[i][kp];
    }
  } else if (bid < 432) {  // V@Wo per (head, d-tile), f32 compute
    int idx = bid - 288, hh = idx / 12, dt = idx % 12, d0 = dt * 64;
#pragma unroll
    for (int p = 0; p < 16; ++p) {
      int i = p * 4 + (tid >> 6), m = tid & 63;
      t0[i][m] = Wv[(size_t)(hh * 768 + d0 + i) * 64 + m];
      t1[i * 64 + m] = Wo[(size_t)(hh * 64 + i) * 64 + m];
    }
    __syncthreads();
    int j = tid & 63;
    for (int p = 0; p < 16; ++p) {
      int i = p * 4 + (tid >> 6);
      float a = 0.f;
      for (int m = 0; m < 64; ++m) a += t0[i][m] * t1[m * 64 + j];
      Wcat[(size_t)(1536 + hh * 64 + j) * 768 + d0 + i] = (f16)a;
    }
  } else {  // bvo
    for (int base = 0; base < 768; base += 256) {
      int idx = base + tid, h2 = idx >> 6, j = idx & 63;
      float a = bo[idx];
      for (int m = 0; m < 64; ++m)
        a += bv[h2 * 64 + m] * Wo[(size_t)(h2 * 64 + m) * 64 + j];
      bvo[idx] = a;
    }
  }
}

__global__ __launch_bounds__(256) void x_to_f16(const float* __restrict__ x,
                                                f16* __restrict__ xh) {
  size_t i = (size_t)blockIdx.x * 256 + threadIdx.x;
  float4 v = reinterpret_cast<const float4*>(x)[i];
  f16x4 o;
  o[0] = (f16)v.x; o[1] = (f16)v.y; o[2] = (f16)v.z; o[3] = (f16)v.w;
  reinterpret_cast<f16x4*>(xh)[i] = o;
}

// ---------------------------------------------------------------------------
// Fused Q/K/Vtilde projection: [8192 x 768] @ [768 x 2304] (B^T layout).
// 128x128 tile, 4 waves, 16x16x32 f16 MFMA, BK=32. Staging via
// global_load_lds width=16 into a 3-buffer LDS ring, 2 tiles prefetched
// ahead, counted s_waitcnt vmcnt(4) (never drained to 0 in steady state) +
// raw s_barrier — T3+T4. LDS dest LINEAR (HW req); conflict-free ds_reads
// preserved by pre-swizzling the GLOBAL source column (read-side XOR cancels).
// Ring safety: stage(t+2) targets the buffer read at t-1; all its readers
// are past this iteration's barrier (their ds_reads completed before their
// MFMAs issued); each wave's vmcnt(4)-then-barrier proves the whole current
// buffer landed (every wave waited on its own quarter's DMAs).
// ---------------------------------------------------------------------------
__global__ __launch_bounds__(256) void qkv_gemm(
    const f16* __restrict__ Xh, const f16* __restrict__ Wcat,
    const float* __restrict__ bq, const float* __restrict__ bk,
    f16* __restrict__ Qo, f16* __restrict__ Ko, f16* __restrict__ Vto) {
  __shared__ __align__(16) f16 Al[3][128 * 32];
  __shared__ __align__(16) f16 Bl[3][128 * 32];
  int tid = threadIdx.x, lane = tid & 63, wid = tid >> 6;
  int l16 = lane & 15, g4 = lane >> 4;
  int r0 = blockIdx.x * 128, n0 = blockIdx.y * 128;
  int wm = wid & 1, wn = wid >> 1;
  f32x4 acc[4][4] = {};

  // per-thread staging geometry: slot s = ss*256+tid, row = s>>2, cs = s&3,
  // source col chunk = cs ^ ((row>>1)&3)  (inverse of the read-side XOR)
  const f16* gA[2];
  const f16* gB[2];
  int ldsoff[2];
#pragma unroll
  for (int ss = 0; ss < 2; ++ss) {
    int s = ss * 256 + tid;
    int row = s >> 2, cs = s & 3;
    int csrc = cs ^ ((row >> 1) & 3);
    gA[ss] = Xh + (size_t)(r0 + row) * 768 + csrc * 8;
    gB[ss] = Wcat + (size_t)(n0 + row) * 768 + csrc * 8;
    ldsoff[ss] = s * 16;  // bytes
  }
  auto stage = [&](int buf, int kk) {
#pragma unroll
    for (int ss = 0; ss < 2; ++ss) {
      gload16(gA[ss] + kk, (char*)Al[buf] + ldsoff[ss]);
      gload16(gB[ss] + kk, (char*)Bl[buf] + ldsoff[ss]);
    }
  };
  auto compute = [&](int cur) {
    f16x8 af[4], bf[4];
#pragma unroll
    for (int mf = 0; mf < 4; ++mf) {
      int row = wm * 64 + mf * 16 + l16;
      int ch = g4 ^ ((row >> 1) & 3);
      af[mf] = *(const f16x8*)(Al[cur] + row * 32 + ch * 8);
    }
#pragma unroll
    for (int nf = 0; nf < 4; ++nf) {
      int row = wn * 64 + nf * 16 + l16;
      int ch = g4 ^ ((row >> 1) & 3);
      bf[nf] = *(const f16x8*)(Bl[cur] + row * 32 + ch * 8);
    }
#pragma unroll
    for (int mf = 0; mf < 4; ++mf)
#pragma unroll
      for (int nf = 0; nf < 4; ++nf)
        acc[mf][nf] = __builtin_amdgcn_mfma_f32_16x16x32_f16(af[mf], bf[nf],
                                                             acc[mf][nf], 0, 0, 0);
  };

  stage(0, 0);     // tile 0
  stage(1, 32);    // tile 1   (8 DMAs/wave outstanding)
#pragma unroll 1
  for (int o = 0; o < 7; ++o) {  // iterations 0..20
#pragma unroll
    for (int i = 0; i < 3; ++i) {
      asm volatile("s_waitcnt vmcnt(4)" ::: "memory");  // own oldest 4 landed
      __builtin_amdgcn_s_barrier();                     // => whole buffer landed
      asm volatile("" ::: "memory");
      stage((i + 2) % 3, (o * 3 + i + 2) * 32);
      compute(i);
    }
  }
  // it=21: cur=0, stage last tile (23) into b2
  asm volatile("s_waitcnt vmcnt(4)" ::: "memory");
  __builtin_amdgcn_s_barrier();
  asm volatile("" ::: "memory");
  stage(2, 23 * 32);
  compute(0);
  // it=22: cur=1
  asm volatile("s_waitcnt vmcnt(4)" ::: "memory");
  __builtin_amdgcn_s_barrier();
  asm volatile("" ::: "memory");
  compute(1);
  // it=23: cur=2
  asm volatile("s_waitcnt vmcnt(0)" ::: "memory");
  __builtin_amdgcn_s_barrier();
  asm volatile("" ::: "memory");
  compute(2);

  // epilogue: bias, (Q only) log2e/8 scale, route to Q / K / Vtilde^T
#pragma unroll
  for (int nf = 0; nf < 4; ++nf) {
    int gcol = n0 + wn * 64 + nf * 16 + l16;
    int sel = gcol / 768, rem = gcol % 768;
    int hh = rem >> 6, kp = rem & 63;
    float bia = sel == 0 ? bq[hh * 64 + kp] : (sel == 1 ? bk[hh * 64 + kp] : 0.f);
    float scl = sel == 0 ? QSCALE : 1.f;
#pragma unroll
    for (int mf = 0; mf < 4; ++mf) {
#pragma unroll
      for (int r = 0; r < 4; ++r) {
        int grow = r0 + wm * 64 + mf * 16 + g4 * 4 + r;
        int b = grow >> 10, s = grow & 1023;
        f16 hv = (f16)((acc[mf][nf][r] + bia) * scl);
        if (sel == 0)
          Qo[((size_t)(b * 12 + hh) * 1024 + s) * 64 + kp] = hv;
        else if (sel == 1)
          Ko[((size_t)(b * 12 + hh) * 1024 + s) * 64 + kp] = hv;
        else
          Vto[((size_t)(b * 12 + hh) * 64 + kp) * 1024 + s] = hv;
      }
    }
  }
}

// ---------------------------------------------------------------------------
// Flash attention, swapped-operand 32x32x16 MFMA, in-register softmax (T12),
// defer-max (T13), Wo folded into Vtilde. Block = (b, h, 128 q-rows), 4 waves
// x 32 q-rows. D-frag of mfma(K,Q): col = q = lane&31 -> each lane owns one
// softmax row (32 of 64 t's; partner lane^32 has the rest). KV tiles 64,
// double-buffered swizzled LDS, 1 barrier/tile. P stays in registers:
// cvt_pkrtz pairs + one xor-32 exchange per kf build the PV B-frags.
// (setprio removed: hurt in R3 — lockstep barrier-synced waves, m190 case.)
// ---------------------------------------------------------------------------
struct SMemKV { f16 K[2][64 * 64]; f16 V[2][64 * 64]; };
union SMemU { SMemKV kv; float O[4 * 32 * 68]; };

__global__ __launch_bounds__(256, 3) void attn_fused(
    const f16* __restrict__ Qg, const f16* __restrict__ Kg,
    const f16* __restrict__ Vt, const float* __restrict__ bvo,
    f16* __restrict__ XhOut, float* __restrict__ Fout, int last) {
  __shared__ __align__(16) SMemU sm;
  int tid = threadIdx.x, lane = tid & 63, wid = tid >> 6;
  int l32 = lane & 31, hi = lane >> 5;
  int q0 = blockIdx.x * 128;
  int hh = blockIdx.y, bb = blockIdx.z;
  size_t bh = (size_t)bb * 12 + hh;
  const f16* Qp = Qg + bh * (1024 * 64);
  const f16* Kp = Kg + bh * (1024 * 64);
  const f16* Vp = Vt + bh * (64 * 1024);

  // Q as B-operand frags: lane -> q-row = q0+wid*32+l32, k = kf*16 + hi*8 + j
  f16x8 qf[4];
#pragma unroll
  for (int kf = 0; kf < 4; ++kf)
    qf[kf] = *(const f16x8*)(Qp + (size_t)(q0 + wid * 32 + l32) * 64 + kf * 16 + hi * 8);

  // staging: 256 threads x 2 chunks each for K and V tiles (64 rows x 8 chunks)
  f16x8 rk[2], rv[2];
  auto kv_load = [&](int t0) {
#pragma unroll
    for (int ss = 0; ss < 2; ++ss) {
      int cl = ss * 256 + tid, r = cl >> 3, c = cl & 7;
      rk[ss] = *(const f16x8*)(Kp + (size_t)(t0 + r) * 64 + c * 8);
      rv[ss] = *(const f16x8*)(Vp + (size_t)r * 1024 + t0 + c * 8);
    }
  };
  auto kv_store = [&](int buf) {
#pragma unroll
    for (int ss = 0; ss < 2; ++ss) {
      int cl = ss * 256 + tid, r = cl >> 3, c = cl & 7;
      int cs = c ^ (r & 7);
      *(f16x8*)(sm.kv.K[buf] + r * 64 + cs * 8) = rk[ss];
      *(f16x8*)(sm.kv.V[buf] + r * 64 + cs * 8) = rv[ss];
    }
  };

  f32x16 oacc0 = {}, oacc1 = {};
  float m = -1e30f, lsum = 0.f;

  kv_load(0);
  kv_store(0);
  __syncthreads();
  int cur = 0;
  for (int t = 0; t < 16; ++t) {
    bool more = t < 15;
    if (more) kv_load((t + 1) * 64);
    const f16* Kc = sm.kv.K[cur];
    const f16* Vc = sm.kv.V[cur];
    // S^T[t][q]: sc0 = t 0..31 tile, sc1 = t 32..63 tile (rows per D-layout)
    f32x16 sc0 = {}, sc1 = {};
#pragma unroll
    for (int kf = 0; kf < 4; ++kf) {
      int ch = (2 * kf + hi) ^ (l32 & 7);
      f16x8 k0 = *(const f16x8*)(Kc + l32 * 64 + ch * 8);
      sc0 = __builtin_amdgcn_mfma_f32_32x32x16_f16(k0, qf[kf], sc0, 0, 0, 0);
      f16x8 k1 = *(const f16x8*)(Kc + (32 + l32) * 64 + ch * 8);
      sc1 = __builtin_amdgcn_mfma_f32_32x32x16_f16(k1, qf[kf], sc1, 0, 0, 0);
    }
    // lane-local row max over 32 values + partner exchange
    float mx[16];
#pragma unroll
    for (int j = 0; j < 16; ++j) mx[j] = fmaxf(sc0[j], sc1[j]);
#pragma unroll
    for (int s = 8; s >= 1; s >>= 1)
#pragma unroll
      for (int j = 0; j < 8; ++j)
        if (j < s) mx[j] = fmaxf(mx[j], mx[j + s]);
    float pmax = fmaxf(mx[0], __shfl_xor(mx[0], 32));
    // defer-max (T13): rescale only when a row grew past THR=8 (exp2 domain)
    if (__any(pmax > m + 8.f)) {
      float mn = fmaxf(m, pmax);
      float c = fexp2(m - mn);
      lsum *= c;
#pragma unroll
      for (int j = 0; j < 16; ++j) { oacc0[j] *= c; oacc1[j] *= c; }
      m = mn;
    }
    // p = exp2(s - m), per-quad: partial sums + packed f16 words
    unsigned w[8][2];
    float qs[8];
#pragma unroll
    for (int qd = 0; qd < 8; ++qd) {
      float a0, a1, a2, a3;
      if (qd < 4) {
        a0 = fexp2(sc0[qd * 4 + 0] - m); a1 = fexp2(sc0[qd * 4 + 1] - m);
        a2 = fexp2(sc0[qd * 4 + 2] - m); a3 = fexp2(sc0[qd * 4 + 3] - m);
      } else {
        a0 = fexp2(sc1[(qd - 4) * 4 + 0] - m); a1 = fexp2(sc1[(qd - 4) * 4 + 1] - m);
        a2 = fexp2(sc1[(qd - 4) * 4 + 2] - m); a3 = fexp2(sc1[(qd - 4) * 4 + 3] - m);
      }
      qs[qd] = (a0 + a1) + (a2 + a3);
      w[qd][0] = __builtin_bit_cast(unsigned, __builtin_amdgcn_cvt_pkrtz(a0, a1));
      w[qd][1] = __builtin_bit_cast(unsigned, __builtin_amdgcn_cvt_pkrtz(a2, a3));
    }
    lsum += ((qs[0] + qs[1]) + (qs[2] + qs[3])) + ((qs[4] + qs[5]) + (qs[6] + qs[7]));
    // PV: per kf build P^T B-frag (own quad + partner quad via xor-32), 2 MFMAs
#pragma unroll
    for (int kf = 0; kf < 4; ++kf) {
      int QB = (kf >> 1) * 4 + 2 * (kf & 1);
      unsigned lo0, lo1, hi0, hi1;
      {
        unsigned s0 = hi ? w[QB][0] : w[QB + 1][0];
        unsigned s1 = hi ? w[QB][1] : w[QB + 1][1];
        unsigned r0 = __shfl_xor(s0, 32);
        unsigned r1 = __shfl_xor(s1, 32);
        lo0 = hi ? r0 : w[QB][0];
        lo1 = hi ? r1 : w[QB][1];
        hi0 = hi ? w[QB + 1][0] : r0;
        hi1 = hi ? w[QB + 1][1] : r1;
      }
      u32x4 pw = {lo0, lo1, hi0, hi1};
      f16x8 pf = __builtin_bit_cast(f16x8, pw);
      int ch = (2 * kf + hi) ^ (l32 & 7);
      f16x8 v0 = *(const f16x8*)(Vc + l32 * 64 + ch * 8);
      oacc0 = __builtin_amdgcn_mfma_f32_32x32x16_f16(v0, pf, oacc0, 0, 0, 0);
      f16x8 v1 = *(const f16x8*)(Vc + (32 + l32) * 64 + ch * 8);
      oacc1 = __builtin_amdgcn_mfma_f32_32x32x16_f16(v1, pf, oacc1, 0, 0, 0);
    }
    if (more) {
      kv_store(cur ^ 1);
      __syncthreads();
      cur ^= 1;
    }
  }
  // epilogue: normalize, transpose via LDS (reuses KV space), coalesced write
  float lt = lsum + __shfl_xor(lsum, 32);
  float inv = 1.f / lt;
  __syncthreads();
  float* Ow = sm.O + wid * (32 * 68) + l32 * 68;
#pragma unroll
  for (int dt = 0; dt < 2; ++dt) {
#pragma unroll
    for (int g = 0; g < 4; ++g) {
      int d0 = dt * 32 + g * 8 + hi * 4;
      f32x4 st;
      if (dt == 0) {
        st[0] = oacc0[g * 4 + 0] * inv; st[1] = oacc0[g * 4 + 1] * inv;
        st[2] = oacc0[g * 4 + 2] * inv; st[3] = oacc0[g * 4 + 3] * inv;
      } else {
        st[0] = oacc1[g * 4 + 0] * inv; st[1] = oacc1[g * 4 + 1] * inv;
        st[2] = oacc1[g * 4 + 2] * inv; st[3] = oacc1[g * 4 + 3] * inv;
      }
      *(f32x4*)(Ow + d0) = st;
    }
  }
  __syncthreads();
  int base_q = bb * 1024 + q0;
#pragma unroll
  for (int p = 0; p < 8; ++p) {
    int cl = p * 256 + tid;
    int row = cl >> 4, c = cl & 15;
    f32x4 v = *(const f32x4*)(sm.O + (row >> 5) * (32 * 68) + (row & 31) * 68 + c * 4);
    float4 bv4 = *(const float4*)(bvo + hh * 64 + c * 4);
    v[0] += bv4.x; v[1] += bv4.y; v[2] += bv4.z; v[3] += bv4.w;
    size_t off = (size_t)(base_q + row) * 768 + hh * 64 + c * 4;
    if (last) {
      *(f32x4*)(Fout + off) = v;
    } else {
      f16x4 hq;
      hq[0] = (f16)v[0]; hq[1] = (f16)v[1]; hq[2] = (f16)v[2]; hq[3] = (f16)v[3];
      *(f16x4*)(XhOut + off) = hq;
    }
  }
}

// ---------------------------------------------------------------------------
extern "C" void kernel_launch(void* const* d_in, const int* in_sizes, int n_in,
                              void* d_out, int out_size, void* d_ws,
                              size_t ws_size, hipStream_t stream) {
  const float* x = (const float*)d_in[0];
  const float* Wq = (const float*)d_in[1];
  const float* bq = (const float*)d_in[2];
  const float* Wk = (const float*)d_in[3];
  const float* bk = (const float*)d_in[4];
  const float* Wv = (const float*)d_in[5];
  const float* bv = (const float*)d_in[6];
  const float* Wo = (const float*)d_in[7];
  const float* bo = (const float*)d_in[8];
  float* out = (float*)d_out;

  char* ws = (char*)d_ws;
  size_t off = 0;
  auto alloc = [&](size_t bytes) -> void* {
    void* p = ws + off;
    off += (bytes + 255) & ~(size_t)255;
    return p;
  };
  f16* Wcat = (f16*)alloc((size_t)NQKV3 * ND * 2);  // 3.54 MB
  float* bvo = (float*)alloc(768 * 4);
  f16* Xh = (f16*)alloc((size_t)NM * ND * 2);   // 12.6 MB
  f16* Qb = (f16*)alloc((size_t)NM * ND * 2);   // B*H*S*HD
  f16* Kb = (f16*)alloc((size_t)NM * ND * 2);
  f16* Vtb = (f16*)alloc((size_t)NM * ND * 2);

  prep_weights<<<433, 256, 0, stream>>>(Wq, Wk, Wv, Wo, bv, bo, Wcat, bvo);
  x_to_f16<<<(NM * ND / 4) / 256, 256, 0, stream>>>(x, Xh);
  for (int l = 0; l < NLAYERS; ++l) {
    qkv_gemm<<<dim3(NM / 128, NQKV3 / 128), 256, 0, stream>>>(
        Xh, Wcat, bq, bk, Qb, Kb, Vtb);
    attn_fused<<<dim3(NS / 128, NH, NB), 256, 0, stream>>>(
        Qb, Kb, Vtb, bvo, Xh, out, l == NLAYERS - 1);
  }
}

// Round 7
// 1149.121 us; speedup vs baseline: 1.1002x; 1.1002x over previous
//
#include <hip/hip_runtime.h>

#define NB 8
#define NS 1024
#define ND 768
#define NH 12
#define NHD 64
#define NLAYERS 12
#define NM (NB * NS)   // 8192 rows
#define NQKV3 (3 * ND) // 2304 output cols of fused QKV GEMM
#define QSCALE 0.1803368802f  // (1/8) * log2(e): softmax runs in exp2 domain

typedef _Float16 f16;
typedef _Float16 f16x8 __attribute__((ext_vector_type(8)));
typedef _Float16 f16x4 __attribute__((ext_vector_type(4)));
typedef _Float16 f16x2 __attribute__((ext_vector_type(2)));
typedef float f32x4 __attribute__((ext_vector_type(4)));
typedef float f32x16 __attribute__((ext_vector_type(16)));
typedef unsigned int u32x4 __attribute__((ext_vector_type(4)));

__device__ inline float fexp2(float x) {
  float r;
  asm("v_exp_f32 %0, %1" : "=v"(r) : "v"(x));
  return r;
}

// ---------------------------------------------------------------------------
// One-time weight prep.
//  Wcat[n][d] (f16, B^T layout), n = sel*768 + h*64 + kp:
//    sel 0: Wq[h][d][kp]   sel 1: Wk[h][d][kp]   sel 2: (Wv@Wo)[h][d][kp]
//  bvo[h*64+j] = sum_m bv[h][m]*Wo[h][m][j] + bo[h][j]
// ---------------------------------------------------------------------------
__global__ __launch_bounds__(256) void prep_weights(
    const float* __restrict__ Wq, const float* __restrict__ Wk,
    const float* __restrict__ Wv, const float* __restrict__ Wo,
    const float* __restrict__ bv, const float* __restrict__ bo,
    f16* __restrict__ Wcat, float* __restrict__ bvo) {
  __shared__ float t0[64][65];
  __shared__ float t1[64 * 64];
  int bid = blockIdx.x, tid = threadIdx.x;
  if (bid < 288) {  // Q,K transposes
    int dt = bid % 12, hh = (bid / 12) % 12, sel = bid / 144;
    const float* W = sel == 0 ? Wq : Wk;
    int d0 = dt * 64;
#pragma unroll
    for (int p = 0; p < 16; ++p) {
      int i = p * 4 + (tid >> 6), kp = tid & 63;
      t0[i][kp] = W[(size_t)(hh * 768 + d0 + i) * 64 + kp];
    }
    __syncthreads();
#pragma unroll
    for (int p = 0; p < 16; ++p) {
      int kp = p * 4 + (tid >> 6), i = tid & 63;
      Wcat[(size_t)(sel * 768 + hh * 64 + kp) * 768 + d0 + i] = (f16)t0[i][kp];
    }
  } else if (bid < 432) {  // V@Wo per (head, d-tile), f32 compute
    int idx = bid - 288, hh = idx / 12, dt = idx % 12, d0 = dt * 64;
#pragma unroll
    for (int p = 0; p < 16; ++p) {
      int i = p * 4 + (tid >> 6), m = tid & 63;
      t0[i][m] = Wv[(size_t)(hh * 768 + d0 + i) * 64 + m];
      t1[i * 64 + m] = Wo[(size_t)(hh * 64 + i) * 64 + m];
    }
    __syncthreads();
    int j = tid & 63;
    for (int p = 0; p < 16; ++p) {
      int i = p * 4 + (tid >> 6);
      float a = 0.f;
      for (int m = 0; m < 64; ++m) a += t0[i][m] * t1[m * 64 + j];
      Wcat[(size_t)(1536 + hh * 64 + j) * 768 + d0 + i] = (f16)a;
    }
  } else {  // bvo
    for (int base = 0; base < 768; base += 256) {
      int idx = base + tid, h2 = idx >> 6, j = idx & 63;
      float a = bo[idx];
      for (int m = 0; m < 64; ++m)
        a += bv[h2 * 64 + m] * Wo[(size_t)(h2 * 64 + m) * 64 + j];
      bvo[idx] = a;
    }
  }
}

__global__ __launch_bounds__(256) void x_to_f16(const float* __restrict__ x,
                                                f16* __restrict__ xh) {
  size_t i = (size_t)blockIdx.x * 256 + threadIdx.x;
  float4 v = reinterpret_cast<const float4*>(x)[i];
  f16x4 o;
  o[0] = (f16)v.x; o[1] = (f16)v.y; o[2] = (f16)v.z; o[3] = (f16)v.w;
  reinterpret_cast<f16x4*>(xh)[i] = o;
}

// ---------------------------------------------------------------------------
// Fused Q/K/Vtilde projection: [8192 x 768] @ [768 x 2304] (B^T layout).
// 256x128 tile, 4 waves (2 M-halves x 2 N-halves), per-wave 128x64 output
// (acc[8][4]) -> 32 MFMA per wave per BK=32 step (2x density of the 128x128
// tile; staging latency per interval unchanged -> better hidden).
// Reg-staged double-buffered LDS (proven best in R2), one barrier per step.
// Q pre-scaled by log2e/8. Each block is a single sel (n0/768 uniform).
// V-blocks transpose through LDS -> fully coalesced Vtilde^T writes.
// ---------------------------------------------------------------------------
#define QK_ASLOTS (256 * 32)  // f16 elems per A buffer
#define QK_BSLOTS (128 * 32)
__global__ __launch_bounds__(256, 2) void qkv_gemm(
    const f16* __restrict__ Xh, const f16* __restrict__ Wcat,
    const float* __restrict__ bq, const float* __restrict__ bk,
    f16* __restrict__ Qo, f16* __restrict__ Ko, f16* __restrict__ Vto) {
  __shared__ __align__(16) f16 SH[2 * QK_ASLOTS + 2 * QK_BSLOTS];  // 48 KB
  int tid = threadIdx.x, lane = tid & 63, wid = tid >> 6;
  int l16 = lane & 15, g4 = lane >> 4;
  int r0 = blockIdx.x * 256, n0 = blockIdx.y * 128;
  int wm = wid & 1, wn = wid >> 1;
  f32x4 acc[8][4] = {};
  f16x8 ra[4], rb[2];

  auto Abuf = [&](int buf) -> f16* { return SH + buf * QK_ASLOTS; };
  auto Bbuf = [&](int buf) -> f16* { return SH + 2 * QK_ASLOTS + buf * QK_BSLOTS; };

  auto load_ab = [&](int kk) {
#pragma unroll
    for (int ss = 0; ss < 4; ++ss) {
      int s = ss * 256 + tid, row = s >> 2, cs = s & 3;
      int csrc = cs ^ ((row >> 1) & 3);
      ra[ss] = *(const f16x8*)(Xh + (size_t)(r0 + row) * 768 + kk + csrc * 8);
    }
#pragma unroll
    for (int ss = 0; ss < 2; ++ss) {
      int s = ss * 256 + tid, row = s >> 2, cs = s & 3;
      int csrc = cs ^ ((row >> 1) & 3);
      rb[ss] = *(const f16x8*)(Wcat + (size_t)(n0 + row) * 768 + kk + csrc * 8);
    }
  };
  auto store_ab = [&](int buf) {
    f16* A = Abuf(buf);
    f16* B = Bbuf(buf);
#pragma unroll
    for (int ss = 0; ss < 4; ++ss) {
      int s = ss * 256 + tid;
      *(f16x8*)(A + s * 8) = ra[ss];
    }
#pragma unroll
    for (int ss = 0; ss < 2; ++ss) {
      int s = ss * 256 + tid;
      *(f16x8*)(B + s * 8) = rb[ss];
    }
  };
  auto compute = [&](int buf) {
    const f16* A = Abuf(buf);
    const f16* B = Bbuf(buf);
    f16x8 af[8], bf[4];
#pragma unroll
    for (int mf = 0; mf < 8; ++mf) {
      int row = wm * 128 + mf * 16 + l16;
      int ch = g4 ^ ((row >> 1) & 3);
      af[mf] = *(const f16x8*)(A + row * 32 + ch * 8);
    }
#pragma unroll
    for (int nf = 0; nf < 4; ++nf) {
      int row = wn * 64 + nf * 16 + l16;
      int ch = g4 ^ ((row >> 1) & 3);
      bf[nf] = *(const f16x8*)(B + row * 32 + ch * 8);
    }
#pragma unroll
    for (int mf = 0; mf < 8; ++mf)
#pragma unroll
      for (int nf = 0; nf < 4; ++nf)
        acc[mf][nf] = __builtin_amdgcn_mfma_f32_16x16x32_f16(af[mf], bf[nf],
                                                             acc[mf][nf], 0, 0, 0);
  };

  load_ab(0);
  store_ab(0);
  __syncthreads();
  int cur = 0;
  for (int kk = 0; kk < 768; kk += 32) {
    bool more = kk + 32 < 768;
    if (more) load_ab(kk + 32);  // global->reg, overlaps MFMAs below
    compute(cur);
    if (more) {
      store_ab(cur ^ 1);  // vmcnt wait lands here, not at a dead barrier
      __syncthreads();
      cur ^= 1;
    }
  }

  int sel = n0 / 768;  // uniform per block (768 % 128 == 0)
  if (sel < 2) {
    // Q / K: bias, (Q only) log2e/8 scale
    const float* bp = sel == 0 ? bq : bk;
    float scl = sel == 0 ? QSCALE : 1.f;
#pragma unroll
    for (int nf = 0; nf < 4; ++nf) {
      int rem = (n0 % 768) + wn * 64 + nf * 16 + l16;
      int hh = rem >> 6, kp = rem & 63;
      float bia = bp[hh * 64 + kp];
#pragma unroll
      for (int mf = 0; mf < 8; ++mf) {
#pragma unroll
        for (int r = 0; r < 4; ++r) {
          int grow = r0 + wm * 128 + mf * 16 + g4 * 4 + r;
          int b = grow >> 10, s = grow & 1023;
          f16 hv = (f16)((acc[mf][nf][r] + bia) * scl);
          f16* dst = sel == 0 ? Qo : Ko;
          dst[((size_t)(b * 12 + hh) * 1024 + s) * 64 + kp] = hv;
        }
      }
    }
  } else {
    // Vtilde^T via LDS transpose: acc -> Lt[c][row] (stride 130), then
    // coalesced f16x2 row writes (256B per wave-store).
    __syncthreads();  // all ds_reads of A/B done before reuse
    f16* Lt = SH;     // 128 cols x 130 stride = 33.3 KB
    int remBase = n0 - 1536;
#pragma unroll
    for (int rh = 0; rh < 2; ++rh) {
      if (wm == rh) {
#pragma unroll
        for (int nf = 0; nf < 4; ++nf) {
          int c = wn * 64 + nf * 16 + l16;
#pragma unroll
          for (int mf = 0; mf < 8; ++mf)
#pragma unroll
            for (int r = 0; r < 4; ++r)
              Lt[c * 130 + mf * 16 + g4 * 4 + r] = (f16)acc[mf][nf][r];
        }
      }
      __syncthreads();
      int bglob = (r0 + rh * 128) >> 10;
      int s0 = (r0 + rh * 128) & 1023;
#pragma unroll
      for (int cc = 0; cc < 32; ++cc) {
        int c = wid * 32 + cc;
        int rem = remBase + c;
        int hh = rem >> 6, kp = rem & 63;
        f16x2 val = *(const f16x2*)(Lt + c * 130 + lane * 2);
        *(f16x2*)(Vto + ((size_t)(bglob * 12 + hh) * 64 + kp) * 1024 + s0 +
                  lane * 2) = val;
      }
      __syncthreads();
    }
  }
}

// ---------------------------------------------------------------------------
// Flash attention (R2-exact best variant), swapped-operand 32x32x16 MFMA,
// in-register softmax (T12), defer-max (T13), Wo folded into Vtilde.
// ---------------------------------------------------------------------------
struct SMemKV { f16 K[2][64 * 64]; f16 V[2][64 * 64]; };
union SMemU { SMemKV kv; float O[4 * 32 * 68]; };

__global__ __launch_bounds__(256, 3) void attn_fused(
    const f16* __restrict__ Qg, const f16* __restrict__ Kg,
    const f16* __restrict__ Vt, const float* __restrict__ bvo,
    f16* __restrict__ XhOut, float* __restrict__ Fout, int last) {
  __shared__ __align__(16) SMemU sm;
  int tid = threadIdx.x, lane = tid & 63, wid = tid >> 6;
  int l32 = lane & 31, hi = lane >> 5;
  int q0 = blockIdx.x * 128;
  int hh = blockIdx.y, bb = blockIdx.z;
  size_t bh = (size_t)bb * 12 + hh;
  const f16* Qp = Qg + bh * (1024 * 64);
  const f16* Kp = Kg + bh * (1024 * 64);
  const f16* Vp = Vt + bh * (64 * 1024);

  f16x8 qf[4];
#pragma unroll
  for (int kf = 0; kf < 4; ++kf)
    qf[kf] = *(const f16x8*)(Qp + (size_t)(q0 + wid * 32 + l32) * 64 + kf * 16 + hi * 8);

  f16x8 rk[2], rv[2];
  auto kv_load = [&](int t0) {
#pragma unroll
    for (int ss = 0; ss < 2; ++ss) {
      int cl = ss * 256 + tid, r = cl >> 3, c = cl & 7;
      rk[ss] = *(const f16x8*)(Kp + (size_t)(t0 + r) * 64 + c * 8);
      rv[ss] = *(const f16x8*)(Vp + (size_t)r * 1024 + t0 + c * 8);
    }
  };
  auto kv_store = [&](int buf) {
#pragma unroll
    for (int ss = 0; ss < 2; ++ss) {
      int cl = ss * 256 + tid, r = cl >> 3, c = cl & 7;
      int cs = c ^ (r & 7);
      *(f16x8*)(sm.kv.K[buf] + r * 64 + cs * 8) = rk[ss];
      *(f16x8*)(sm.kv.V[buf] + r * 64 + cs * 8) = rv[ss];
    }
  };

  f32x16 oacc0 = {}, oacc1 = {};
  float m = -1e30f, lsum = 0.f;

  kv_load(0);
  kv_store(0);
  __syncthreads();
  int cur = 0;
  for (int t = 0; t < 16; ++t) {
    bool more = t < 15;
    if (more) kv_load((t + 1) * 64);
    const f16* Kc = sm.kv.K[cur];
    const f16* Vc = sm.kv.V[cur];
    f32x16 sc0 = {}, sc1 = {};
#pragma unroll
    for (int kf = 0; kf < 4; ++kf) {
      int ch = (2 * kf + hi) ^ (l32 & 7);
      f16x8 k0 = *(const f16x8*)(Kc + l32 * 64 + ch * 8);
      sc0 = __builtin_amdgcn_mfma_f32_32x32x16_f16(k0, qf[kf], sc0, 0, 0, 0);
      f16x8 k1 = *(const f16x8*)(Kc + (32 + l32) * 64 + ch * 8);
      sc1 = __builtin_amdgcn_mfma_f32_32x32x16_f16(k1, qf[kf], sc1, 0, 0, 0);
    }
    float mx[16];
#pragma unroll
    for (int j = 0; j < 16; ++j) mx[j] = fmaxf(sc0[j], sc1[j]);
#pragma unroll
    for (int s = 8; s >= 1; s >>= 1)
#pragma unroll
      for (int j = 0; j < 8; ++j)
        if (j < s) mx[j] = fmaxf(mx[j], mx[j + s]);
    float pmax = fmaxf(mx[0], __shfl_xor(mx[0], 32));
    if (__any(pmax > m + 8.f)) {
      float mn = fmaxf(m, pmax);
      float c = fexp2(m - mn);
      lsum *= c;
#pragma unroll
      for (int j = 0; j < 16; ++j) { oacc0[j] *= c; oacc1[j] *= c; }
      m = mn;
    }
    unsigned w[8][2];
    float qs[8];
#pragma unroll
    for (int qd = 0; qd < 8; ++qd) {
      float a0, a1, a2, a3;
      if (qd < 4) {
        a0 = fexp2(sc0[qd * 4 + 0] - m); a1 = fexp2(sc0[qd * 4 + 1] - m);
        a2 = fexp2(sc0[qd * 4 + 2] - m); a3 = fexp2(sc0[qd * 4 + 3] - m);
      } else {
        a0 = fexp2(sc1[(qd - 4) * 4 + 0] - m); a1 = fexp2(sc1[(qd - 4) * 4 + 1] - m);
        a2 = fexp2(sc1[(qd - 4) * 4 + 2] - m); a3 = fexp2(sc1[(qd - 4) * 4 + 3] - m);
      }
      qs[qd] = (a0 + a1) + (a2 + a3);
      w[qd][0] = __builtin_bit_cast(unsigned, __builtin_amdgcn_cvt_pkrtz(a0, a1));
      w[qd][1] = __builtin_bit_cast(unsigned, __builtin_amdgcn_cvt_pkrtz(a2, a3));
    }
    lsum += ((qs[0] + qs[1]) + (qs[2] + qs[3])) + ((qs[4] + qs[5]) + (qs[6] + qs[7]));
#pragma unroll
    for (int kf = 0; kf < 4; ++kf) {
      int QB = (kf >> 1) * 4 + 2 * (kf & 1);
      unsigned lo0, lo1, hi0, hi1;
      {
        unsigned s0 = hi ? w[QB][0] : w[QB + 1][0];
        unsigned s1 = hi ? w[QB][1] : w[QB + 1][1];
        unsigned r0 = __shfl_xor(s0, 32);
        unsigned r1 = __shfl_xor(s1, 32);
        lo0 = hi ? r0 : w[QB][0];
        lo1 = hi ? r1 : w[QB][1];
        hi0 = hi ? w[QB + 1][0] : r0;
        hi1 = hi ? w[QB + 1][1] : r1;
      }
      u32x4 pw = {lo0, lo1, hi0, hi1};
      f16x8 pf = __builtin_bit_cast(f16x8, pw);
      int ch = (2 * kf + hi) ^ (l32 & 7);
      f16x8 v0 = *(const f16x8*)(Vc + l32 * 64 + ch * 8);
      oacc0 = __builtin_amdgcn_mfma_f32_32x32x16_f16(v0, pf, oacc0, 0, 0, 0);
      f16x8 v1 = *(const f16x8*)(Vc + (32 + l32) * 64 + ch * 8);
      oacc1 = __builtin_amdgcn_mfma_f32_32x32x16_f16(v1, pf, oacc1, 0, 0, 0);
    }
    if (more) {
      kv_store(cur ^ 1);
      __syncthreads();
      cur ^= 1;
    }
  }
  float lt = lsum + __shfl_xor(lsum, 32);
  float inv = 1.f / lt;
  __syncthreads();
  float* Ow = sm.O + wid * (32 * 68) + l32 * 68;
#pragma unroll
  for (int dt = 0; dt < 2; ++dt) {
#pragma unroll
    for (int g = 0; g < 4; ++g) {
      int d0 = dt * 32 + g * 8 + hi * 4;
      f32x4 st;
      if (dt == 0) {
        st[0] = oacc0[g * 4 + 0] * inv; st[1] = oacc0[g * 4 + 1] * inv;
        st[2] = oacc0[g * 4 + 2] * inv; st[3] = oacc0[g * 4 + 3] * inv;
      } else {
        st[0] = oacc1[g * 4 + 0] * inv; st[1] = oacc1[g * 4 + 1] * inv;
        st[2] = oacc1[g * 4 + 2] * inv; st[3] = oacc1[g * 4 + 3] * inv;
      }
      *(f32x4*)(Ow + d0) = st;
    }
  }
  __syncthreads();
  int base_q = bb * 1024 + q0;
#pragma unroll
  for (int p = 0; p < 8; ++p) {
    int cl = p * 256 + tid;
    int row = cl >> 4, c = cl & 15;
    f32x4 v = *(const f32x4*)(sm.O + (row >> 5) * (32 * 68) + (row & 31) * 68 + c * 4);
    float4 bv4 = *(const float4*)(bvo + hh * 64 + c * 4);
    v[0] += bv4.x; v[1] += bv4.y; v[2] += bv4.z; v[3] += bv4.w;
    size_t off = (size_t)(base_q + row) * 768 + hh * 64 + c * 4;
    if (last) {
      *(f32x4*)(Fout + off) = v;
    } else {
      f16x4 hq;
      hq[0] = (f16)v[0]; hq[1] = (f16)v[1]; hq[2] = (f16)v[2]; hq[3] = (f16)v[3];
      *(f16x4*)(XhOut + off) = hq;
    }
  }
}

// ---------------------------------------------------------------------------
extern "C" void kernel_launch(void* const* d_in, const int* in_sizes, int n_in,
                              void* d_out, int out_size, void* d_ws,
                              size_t ws_size, hipStream_t stream) {
  const float* x = (const float*)d_in[0];
  const float* Wq = (const float*)d_in[1];
  const float* bq = (const float*)d_in[2];
  const float* Wk = (const float*)d_in[3];
  const float* bk = (const float*)d_in[4];
  const float* Wv = (const float*)d_in[5];
  const float* bv = (const float*)d_in[6];
  const float* Wo = (const float*)d_in[7];
  const float* bo = (const float*)d_in[8];
  float* out = (float*)d_out;

  char* ws = (char*)d_ws;
  size_t off = 0;
  auto alloc = [&](size_t bytes) -> void* {
    void* p = ws + off;
    off += (bytes + 255) & ~(size_t)255;
    return p;
  };
  f16* Wcat = (f16*)alloc((size_t)NQKV3 * ND * 2);  // 3.54 MB
  float* bvo = (float*)alloc(768 * 4);
  f16* Xh = (f16*)alloc((size_t)NM * ND * 2);   // 12.6 MB
  f16* Qb = (f16*)alloc((size_t)NM * ND * 2);   // B*H*S*HD
  f16* Kb = (f16*)alloc((size_t)NM * ND * 2);
  f16* Vtb = (f16*)alloc((size_t)NM * ND * 2);

  prep_weights<<<433, 256, 0, stream>>>(Wq, Wk, Wv, Wo, bv, bo, Wcat, bvo);
  x_to_f16<<<(NM * ND / 4) / 256, 256, 0, stream>>>(x, Xh);
  for (int l = 0; l < NLAYERS; ++l) {
    qkv_gemm<<<dim3(NM / 256, NQKV3 / 128), 256, 0, stream>>>(
        Xh, Wcat, bq, bk, Qb, Kb, Vtb);
    attn_fused<<<dim3(NS / 128, NH, NB), 256, 0, stream>>>(
        Qb, Kb, Vtb, bvo, Xh, out, l == NLAYERS - 1);
  }
}

// Round 8
// 959.810 us; speedup vs baseline: 1.3172x; 1.1972x over previous
//
#include <hip/hip_runtime.h>

#define NB 8
#define NS 1024
#define ND 768
#define NH 12
#define NHD 64
#define NLAYERS 12
#define NM (NB * NS)   // 8192 rows
#define NQKV3 (3 * ND) // 2304 output cols of fused QKV GEMM
#define QSCALE 0.1803368802f  // (1/8) * log2(e): softmax runs in exp2 domain

typedef _Float16 f16;
typedef _Float16 f16x8 __attribute__((ext_vector_type(8)));
typedef _Float16 f16x4 __attribute__((ext_vector_type(4)));
typedef _Float16 f16x2 __attribute__((ext_vector_type(2)));
typedef float f32x4 __attribute__((ext_vector_type(4)));
typedef float f32x16 __attribute__((ext_vector_type(16)));
typedef unsigned int u32x4 __attribute__((ext_vector_type(4)));

__device__ inline float fexp2(float x) {
  float r;
  asm("v_exp_f32 %0, %1" : "=v"(r) : "v"(x));
  return r;
}

// ---------------------------------------------------------------------------
// One-time weight prep.
//  Wcat[n][d] (f16, B^T layout), n = sel*768 + h*64 + kp:
//    sel 0: Wq[h][d][kp]   sel 1: Wk[h][d][kp]   sel 2: (Wv@Wo)[h][d][kp]
//  bvo[h*64+j] = sum_m bv[h][m]*Wo[h][m][j] + bo[h][j]
// ---------------------------------------------------------------------------
__global__ __launch_bounds__(256) void prep_weights(
    const float* __restrict__ Wq, const float* __restrict__ Wk,
    const float* __restrict__ Wv, const float* __restrict__ Wo,
    const float* __restrict__ bv, const float* __restrict__ bo,
    f16* __restrict__ Wcat, float* __restrict__ bvo) {
  __shared__ float t0[64][65];
  __shared__ float t1[64 * 64];
  int bid = blockIdx.x, tid = threadIdx.x;
  if (bid < 288) {  // Q,K transposes
    int dt = bid % 12, hh = (bid / 12) % 12, sel = bid / 144;
    const float* W = sel == 0 ? Wq : Wk;
    int d0 = dt * 64;
#pragma unroll
    for (int p = 0; p < 16; ++p) {
      int i = p * 4 + (tid >> 6), kp = tid & 63;
      t0[i][kp] = W[(size_t)(hh * 768 + d0 + i) * 64 + kp];
    }
    __syncthreads();
#pragma unroll
    for (int p = 0; p < 16; ++p) {
      int kp = p * 4 + (tid >> 6), i = tid & 63;
      Wcat[(size_t)(sel * 768 + hh * 64 + kp) * 768 + d0 + i] = (f16)t0[i][kp];
    }
  } else if (bid < 432) {  // V@Wo per (head, d-tile), f32 compute
    int idx = bid - 288, hh = idx / 12, dt = idx % 12, d0 = dt * 64;
#pragma unroll
    for (int p = 0; p < 16; ++p) {
      int i = p * 4 + (tid >> 6), m = tid & 63;
      t0[i][m] = Wv[(size_t)(hh * 768 + d0 + i) * 64 + m];
      t1[i * 64 + m] = Wo[(size_t)(hh * 64 + i) * 64 + m];
    }
    __syncthreads();
    int j = tid & 63;
    for (int p = 0; p < 16; ++p) {
      int i = p * 4 + (tid >> 6);
      float a = 0.f;
      for (int m = 0; m < 64; ++m) a += t0[i][m] * t1[m * 64 + j];
      Wcat[(size_t)(1536 + hh * 64 + j) * 768 + d0 + i] = (f16)a;
    }
  } else {  // bvo
    for (int base = 0; base < 768; base += 256) {
      int idx = base + tid, h2 = idx >> 6, j = idx & 63;
      float a = bo[idx];
      for (int m = 0; m < 64; ++m)
        a += bv[h2 * 64 + m] * Wo[(size_t)(h2 * 64 + m) * 64 + j];
      bvo[idx] = a;
    }
  }
}

__global__ __launch_bounds__(256) void x_to_f16(const float* __restrict__ x,
                                                f16* __restrict__ xh) {
  size_t i = (size_t)blockIdx.x * 256 + threadIdx.x;
  float4 v = reinterpret_cast<const float4*>(x)[i];
  f16x4 o;
  o[0] = (f16)v.x; o[1] = (f16)v.y; o[2] = (f16)v.z; o[3] = (f16)v.w;
  reinterpret_cast<f16x4*>(xh)[i] = o;
}

// ---------------------------------------------------------------------------
// Fused Q/K/Vtilde projection: [8192 x 768] @ [768 x 2304] (B^T layout).
// Tile 128x192, 4 waves (2M x 2N), per-wave 64x96 = acc[4][6], 24 MFMA per
// BK=32 step. Grid = 64 x 12 = 768 blocks = EXACTLY 3 blocks/CU resident
// (LDS 40KB, launch_bounds(256,3)) -> one dispatch round, zero tail — the
// same residency profile as attn_fused (938 TF with the identical 1-barrier
// reg-staged dbuf inner loop; 3 co-resident blocks hide the barrier stall).
// All epilogues route through an LDS transpose (padded strides) -> pure
// coalesced f16x8 stores (fixes write-allocate inflation of 2B scatters).
// ---------------------------------------------------------------------------
#define QK_AS (128 * 32)  // f16 elems per A buffer
#define QK_BS (192 * 32)
__global__ __launch_bounds__(256, 3) void qkv_gemm(
    const f16* __restrict__ Xh, const f16* __restrict__ Wcat,
    const float* __restrict__ bq, const float* __restrict__ bk,
    f16* __restrict__ Qo, f16* __restrict__ Ko, f16* __restrict__ Vto) {
  __shared__ __align__(16) f16 SH[2 * QK_AS + 2 * QK_BS];  // 40 KB
  int tid = threadIdx.x, lane = tid & 63, wid = tid >> 6;
  int l16 = lane & 15, g4 = lane >> 4;
  int r0 = blockIdx.x * 128, n0 = blockIdx.y * 192;
  int wm = wid & 1, wn = wid >> 1;
  f32x4 acc[4][6] = {};
  f16x8 ra[2], rb[3];

  auto Abuf = [&](int buf) -> f16* { return SH + buf * QK_AS; };
  auto Bbuf = [&](int buf) -> f16* { return SH + 2 * QK_AS + buf * QK_BS; };

  auto load_ab = [&](int kk) {
#pragma unroll
    for (int ss = 0; ss < 2; ++ss) {
      int s = ss * 256 + tid, row = s >> 2, cs = s & 3;
      int csrc = cs ^ ((row >> 1) & 3);
      ra[ss] = *(const f16x8*)(Xh + (size_t)(r0 + row) * 768 + kk + csrc * 8);
    }
#pragma unroll
    for (int ss = 0; ss < 3; ++ss) {
      int s = ss * 256 + tid, row = s >> 2, cs = s & 3;
      int csrc = cs ^ ((row >> 1) & 3);
      rb[ss] = *(const f16x8*)(Wcat + (size_t)(n0 + row) * 768 + kk + csrc * 8);
    }
  };
  auto store_ab = [&](int buf) {
    f16* A = Abuf(buf);
    f16* B = Bbuf(buf);
#pragma unroll
    for (int ss = 0; ss < 2; ++ss) *(f16x8*)(A + (ss * 256 + tid) * 8) = ra[ss];
#pragma unroll
    for (int ss = 0; ss < 3; ++ss) *(f16x8*)(B + (ss * 256 + tid) * 8) = rb[ss];
  };
  auto compute = [&](int buf) {
    const f16* A = Abuf(buf);
    const f16* B = Bbuf(buf);
    f16x8 af[4], bf[6];
#pragma unroll
    for (int mf = 0; mf < 4; ++mf) {
      int row = wm * 64 + mf * 16 + l16;
      int ch = g4 ^ ((row >> 1) & 3);
      af[mf] = *(const f16x8*)(A + row * 32 + ch * 8);
    }
#pragma unroll
    for (int nf = 0; nf < 6; ++nf) {
      int row = wn * 96 + nf * 16 + l16;
      int ch = g4 ^ ((row >> 1) & 3);
      bf[nf] = *(const f16x8*)(B + row * 32 + ch * 8);
    }
#pragma unroll
    for (int mf = 0; mf < 4; ++mf)
#pragma unroll
      for (int nf = 0; nf < 6; ++nf)
        acc[mf][nf] = __builtin_amdgcn_mfma_f32_16x16x32_f16(af[mf], bf[nf],
                                                             acc[mf][nf], 0, 0, 0);
  };

  load_ab(0);
  store_ab(0);
  __syncthreads();
  int cur = 0;
  for (int kk = 0; kk < 768; kk += 32) {
    bool more = kk + 32 < 768;
    if (more) load_ab(kk + 32);  // global->reg, overlaps MFMAs below
    compute(cur);
    if (more) {
      store_ab(cur ^ 1);  // vmcnt wait lands here, not at a dead barrier
      __syncthreads();
      cur ^= 1;
    }
  }

  int sel = n0 / 768;   // uniform per block (192*4 = 768)
  int nrem = n0 % 768;  // 0,192,384,576
  __syncthreads();      // all ds_reads of A/B done before SH reuse
  if (sel < 2) {
    // Q/K: bias (+Q scale), LDS transpose [64][208], coalesced f16x8 rows
    const float* bp = sel == 0 ? bq : bk;
    float scl = sel == 0 ? QSCALE : 1.f;
    f16* dst = sel == 0 ? Qo : Ko;
#pragma unroll
    for (int rh = 0; rh < 2; ++rh) {
      if (wm == rh) {
#pragma unroll
        for (int nf = 0; nf < 6; ++nf) {
          int c = wn * 96 + nf * 16 + l16;
          float bia = bp[nrem + c];
#pragma unroll
          for (int mf = 0; mf < 4; ++mf)
#pragma unroll
            for (int r = 0; r < 4; ++r)
              SH[(mf * 16 + g4 * 4 + r) * 208 + c] =
                  (f16)((acc[mf][nf][r] + bia) * scl);
        }
      }
      __syncthreads();
#pragma unroll
      for (int p = 0; p < 6; ++p) {
        int cl = p * 256 + tid;           // 64 rows x 24 chunks
        int lr = cl / 24, ch = cl % 24;
        int grow = r0 + rh * 64 + lr;
        int b = grow >> 10, s = grow & 1023;
        int col = nrem + ch * 8;
        int hh = col >> 6, kp = col & 63;
        f16x8 v = *(const f16x8*)(SH + lr * 208 + ch * 8);
        *(f16x8*)(dst + ((size_t)(b * 12 + hh) * 1024 + s) * 64 + kp) = v;
      }
      __syncthreads();
    }
  } else {
    // Vtilde^T: LDS transpose [192][72] (col-major), coalesced f16x8 along s
#pragma unroll
    for (int rh = 0; rh < 2; ++rh) {
      if (wm == rh) {
#pragma unroll
        for (int nf = 0; nf < 6; ++nf) {
          int c = wn * 96 + nf * 16 + l16;
#pragma unroll
          for (int mf = 0; mf < 4; ++mf)
#pragma unroll
            for (int r = 0; r < 4; ++r)
              SH[c * 72 + mf * 16 + g4 * 4 + r] = (f16)acc[mf][nf][r];
        }
      }
      __syncthreads();
      int grow0 = r0 + rh * 64;
      int b = grow0 >> 10, s0 = grow0 & 1023;
#pragma unroll
      for (int p = 0; p < 6; ++p) {
        int cl = p * 256 + tid;  // 192 cols x 8 chunks
        int c = cl >> 3, ch = cl & 7;
        int col = nrem + c;
        int hh = col >> 6, kp = col & 63;
        f16x8 v = *(const f16x8*)(SH + c * 72 + ch * 8);
        *(f16x8*)(Vto + ((size_t)(b * 12 + hh) * 64 + kp) * 1024 + s0 + ch * 8) = v;
      }
      __syncthreads();
    }
  }
}

// ---------------------------------------------------------------------------
// Flash attention (R2-exact best variant), swapped-operand 32x32x16 MFMA,
// in-register softmax (T12), defer-max (T13), Wo folded into Vtilde.
// ---------------------------------------------------------------------------
struct SMemKV { f16 K[2][64 * 64]; f16 V[2][64 * 64]; };
union SMemU { SMemKV kv; float O[4 * 32 * 68]; };

__global__ __launch_bounds__(256, 3) void attn_fused(
    const f16* __restrict__ Qg, const f16* __restrict__ Kg,
    const f16* __restrict__ Vt, const float* __restrict__ bvo,
    f16* __restrict__ XhOut, float* __restrict__ Fout, int last) {
  __shared__ __align__(16) SMemU sm;
  int tid = threadIdx.x, lane = tid & 63, wid = tid >> 6;
  int l32 = lane & 31, hi = lane >> 5;
  int q0 = blockIdx.x * 128;
  int hh = blockIdx.y, bb = blockIdx.z;
  size_t bh = (size_t)bb * 12 + hh;
  const f16* Qp = Qg + bh * (1024 * 64);
  const f16* Kp = Kg + bh * (1024 * 64);
  const f16* Vp = Vt + bh * (64 * 1024);

  f16x8 qf[4];
#pragma unroll
  for (int kf = 0; kf < 4; ++kf)
    qf[kf] = *(const f16x8*)(Qp + (size_t)(q0 + wid * 32 + l32) * 64 + kf * 16 + hi * 8);

  f16x8 rk[2], rv[2];
  auto kv_load = [&](int t0) {
#pragma unroll
    for (int ss = 0; ss < 2; ++ss) {
      int cl = ss * 256 + tid, r = cl >> 3, c = cl & 7;
      rk[ss] = *(const f16x8*)(Kp + (size_t)(t0 + r) * 64 + c * 8);
      rv[ss] = *(const f16x8*)(Vp + (size_t)r * 1024 + t0 + c * 8);
    }
  };
  auto kv_store = [&](int buf) {
#pragma unroll
    for (int ss = 0; ss < 2; ++ss) {
      int cl = ss * 256 + tid, r = cl >> 3, c = cl & 7;
      int cs = c ^ (r & 7);
      *(f16x8*)(sm.kv.K[buf] + r * 64 + cs * 8) = rk[ss];
      *(f16x8*)(sm.kv.V[buf] + r * 64 + cs * 8) = rv[ss];
    }
  };

  f32x16 oacc0 = {}, oacc1 = {};
  float m = -1e30f, lsum = 0.f;

  kv_load(0);
  kv_store(0);
  __syncthreads();
  int cur = 0;
  for (int t = 0; t < 16; ++t) {
    bool more = t < 15;
    if (more) kv_load((t + 1) * 64);
    const f16* Kc = sm.kv.K[cur];
    const f16* Vc = sm.kv.V[cur];
    f32x16 sc0 = {}, sc1 = {};
#pragma unroll
    for (int kf = 0; kf < 4; ++kf) {
      int ch = (2 * kf + hi) ^ (l32 & 7);
      f16x8 k0 = *(const f16x8*)(Kc + l32 * 64 + ch * 8);
      sc0 = __builtin_amdgcn_mfma_f32_32x32x16_f16(k0, qf[kf], sc0, 0, 0, 0);
      f16x8 k1 = *(const f16x8*)(Kc + (32 + l32) * 64 + ch * 8);
      sc1 = __builtin_amdgcn_mfma_f32_32x32x16_f16(k1, qf[kf], sc1, 0, 0, 0);
    }
    float mx[16];
#pragma unroll
    for (int j = 0; j < 16; ++j) mx[j] = fmaxf(sc0[j], sc1[j]);
#pragma unroll
    for (int s = 8; s >= 1; s >>= 1)
#pragma unroll
      for (int j = 0; j < 8; ++j)
        if (j < s) mx[j] = fmaxf(mx[j], mx[j + s]);
    float pmax = fmaxf(mx[0], __shfl_xor(mx[0], 32));
    if (__any(pmax > m + 8.f)) {
      float mn = fmaxf(m, pmax);
      float c = fexp2(m - mn);
      lsum *= c;
#pragma unroll
      for (int j = 0; j < 16; ++j) { oacc0[j] *= c; oacc1[j] *= c; }
      m = mn;
    }
    unsigned w[8][2];
    float qs[8];
#pragma unroll
    for (int qd = 0; qd < 8; ++qd) {
      float a0, a1, a2, a3;
      if (qd < 4) {
        a0 = fexp2(sc0[qd * 4 + 0] - m); a1 = fexp2(sc0[qd * 4 + 1] - m);
        a2 = fexp2(sc0[qd * 4 + 2] - m); a3 = fexp2(sc0[qd * 4 + 3] - m);
      } else {
        a0 = fexp2(sc1[(qd - 4) * 4 + 0] - m); a1 = fexp2(sc1[(qd - 4) * 4 + 1] - m);
        a2 = fexp2(sc1[(qd - 4) * 4 + 2] - m); a3 = fexp2(sc1[(qd - 4) * 4 + 3] - m);
      }
      qs[qd] = (a0 + a1) + (a2 + a3);
      w[qd][0] = __builtin_bit_cast(unsigned, __builtin_amdgcn_cvt_pkrtz(a0, a1));
      w[qd][1] = __builtin_bit_cast(unsigned, __builtin_amdgcn_cvt_pkrtz(a2, a3));
    }
    lsum += ((qs[0] + qs[1]) + (qs[2] + qs[3])) + ((qs[4] + qs[5]) + (qs[6] + qs[7]));
#pragma unroll
    for (int kf = 0; kf < 4; ++kf) {
      int QB = (kf >> 1) * 4 + 2 * (kf & 1);
      unsigned lo0, lo1, hi0, hi1;
      {
        unsigned s0 = hi ? w[QB][0] : w[QB + 1][0];
        unsigned s1 = hi ? w[QB][1] : w[QB + 1][1];
        unsigned r0 = __shfl_xor(s0, 32);
        unsigned r1 = __shfl_xor(s1, 32);
        lo0 = hi ? r0 : w[QB][0];
        lo1 = hi ? r1 : w[QB][1];
        hi0 = hi ? w[QB + 1][0] : r0;
        hi1 = hi ? w[QB + 1][1] : r1;
      }
      u32x4 pw = {lo0, lo1, hi0, hi1};
      f16x8 pf = __builtin_bit_cast(f16x8, pw);
      int ch = (2 * kf + hi) ^ (l32 & 7);
      f16x8 v0 = *(const f16x8*)(Vc + l32 * 64 + ch * 8);
      oacc0 = __builtin_amdgcn_mfma_f32_32x32x16_f16(v0, pf, oacc0, 0, 0, 0);
      f16x8 v1 = *(const f16x8*)(Vc + (32 + l32) * 64 + ch * 8);
      oacc1 = __builtin_amdgcn_mfma_f32_32x32x16_f16(v1, pf, oacc1, 0, 0, 0);
    }
    if (more) {
      kv_store(cur ^ 1);
      __syncthreads();
      cur ^= 1;
    }
  }
  float lt = lsum + __shfl_xor(lsum, 32);
  float inv = 1.f / lt;
  __syncthreads();
  float* Ow = sm.O + wid * (32 * 68) + l32 * 68;
#pragma unroll
  for (int dt = 0; dt < 2; ++dt) {
#pragma unroll
    for (int g = 0; g < 4; ++g) {
      int d0 = dt * 32 + g * 8 + hi * 4;
      f32x4 st;
      if (dt == 0) {
        st[0] = oacc0[g * 4 + 0] * inv; st[1] = oacc0[g * 4 + 1] * inv;
        st[2] = oacc0[g * 4 + 2] * inv; st[3] = oacc0[g * 4 + 3] * inv;
      } else {
        st[0] = oacc1[g * 4 + 0] * inv; st[1] = oacc1[g * 4 + 1] * inv;
        st[2] = oacc1[g * 4 + 2] * inv; st[3] = oacc1[g * 4 + 3] * inv;
      }
      *(f32x4*)(Ow + d0) = st;
    }
  }
  __syncthreads();
  int base_q = bb * 1024 + q0;
#pragma unroll
  for (int p = 0; p < 8; ++p) {
    int cl = p * 256 + tid;
    int row = cl >> 4, c = cl & 15;
    f32x4 v = *(const f32x4*)(sm.O + (row >> 5) * (32 * 68) + (row & 31) * 68 + c * 4);
    float4 bv4 = *(const float4*)(bvo + hh * 64 + c * 4);
    v[0] += bv4.x; v[1] += bv4.y; v[2] += bv4.z; v[3] += bv4.w;
    size_t off = (size_t)(base_q + row) * 768 + hh * 64 + c * 4;
    if (last) {
      *(f32x4*)(Fout + off) = v;
    } else {
      f16x4 hq;
      hq[0] = (f16)v[0]; hq[1] = (f16)v[1]; hq[2] = (f16)v[2]; hq[3] = (f16)v[3];
      *(f16x4*)(XhOut + off) = hq;
    }
  }
}

// ---------------------------------------------------------------------------
extern "C" void kernel_launch(void* const* d_in, const int* in_sizes, int n_in,
                              void* d_out, int out_size, void* d_ws,
                              size_t ws_size, hipStream_t stream) {
  const float* x = (const float*)d_in[0];
  const float* Wq = (const float*)d_in[1];
  const float* bq = (const float*)d_in[2];
  const float* Wk = (const float*)d_in[3];
  const float* bk = (const float*)d_in[4];
  const float* Wv = (const float*)d_in[5];
  const float* bv = (const float*)d_in[6];
  const float* Wo = (const float*)d_in[7];
  const float* bo = (const float*)d_in[8];
  float* out = (float*)d_out;

  char* ws = (char*)d_ws;
  size_t off = 0;
  auto alloc = [&](size_t bytes) -> void* {
    void* p = ws + off;
    off += (bytes + 255) & ~(size_t)255;
    return p;
  };
  f16* Wcat = (f16*)alloc((size_t)NQKV3 * ND * 2);  // 3.54 MB
  float* bvo = (float*)alloc(768 * 4);
  f16* Xh = (f16*)alloc((size_t)NM * ND * 2);   // 12.6 MB
  f16* Qb = (f16*)alloc((size_t)NM * ND * 2);   // B*H*S*HD
  f16* Kb = (f16*)alloc((size_t)NM * ND * 2);
  f16* Vtb = (f16*)alloc((size_t)NM * ND * 2);

  prep_weights<<<433, 256, 0, stream>>>(Wq, Wk, Wv, Wo, bv, bo, Wcat, bvo);
  x_to_f16<<<(NM * ND / 4) / 256, 256, 0, stream>>>(x, Xh);
  for (int l = 0; l < NLAYERS; ++l) {
    qkv_gemm<<<dim3(NM / 128, NQKV3 / 192), 256, 0, stream>>>(
        Xh, Wcat, bq, bk, Qb, Kb, Vtb);
    attn_fused<<<dim3(NS / 128, NH, NB), 256, 0, stream>>>(
        Qb, Kb, Vtb, bvo, Xh, out, l == NLAYERS - 1);
  }
}

// Round 9
// 953.633 us; speedup vs baseline: 1.3257x; 1.0065x over previous
//
#include <hip/hip_runtime.h>

#define NB 8
#define NS 1024
#define ND 768
#define NH 12
#define NHD 64
#define NLAYERS 12
#define NM (NB * NS)   // 8192 rows
#define NQKV3 (3 * ND) // 2304 output cols of fused QKV GEMM
#define QSCALE 0.1803368802f  // (1/8) * log2(e): softmax runs in exp2 domain

typedef _Float16 f16;
typedef _Float16 f16x8 __attribute__((ext_vector_type(8)));
typedef _Float16 f16x4 __attribute__((ext_vector_type(4)));
typedef _Float16 f16x2 __attribute__((ext_vector_type(2)));
typedef float f32x4 __attribute__((ext_vector_type(4)));
typedef float f32x16 __attribute__((ext_vector_type(16)));
typedef unsigned int u32x4 __attribute__((ext_vector_type(4)));

__device__ inline float fexp2(float x) {
  float r;
  asm("v_exp_f32 %0, %1" : "=v"(r) : "v"(x));
  return r;
}

// ---------------------------------------------------------------------------
// One-time weight prep.
//  Wcat[n][d] (f16, B^T layout), n = sel*768 + h*64 + kp:
//    sel 0: Wq[h][d][kp]   sel 1: Wk[h][d][kp]   sel 2: (Wv@Wo)[h][d][kp]
//  bvo[h*64+j] = sum_m bv[h][m]*Wo[h][m][j] + bo[h][j]
// ---------------------------------------------------------------------------
__global__ __launch_bounds__(256) void prep_weights(
    const float* __restrict__ Wq, const float* __restrict__ Wk,
    const float* __restrict__ Wv, const float* __restrict__ Wo,
    const float* __restrict__ bv, const float* __restrict__ bo,
    f16* __restrict__ Wcat, float* __restrict__ bvo) {
  __shared__ float t0[64][65];
  __shared__ float t1[64 * 64];
  int bid = blockIdx.x, tid = threadIdx.x;
  if (bid < 288) {  // Q,K transposes
    int dt = bid % 12, hh = (bid / 12) % 12, sel = bid / 144;
    const float* W = sel == 0 ? Wq : Wk;
    int d0 = dt * 64;
#pragma unroll
    for (int p = 0; p < 16; ++p) {
      int i = p * 4 + (tid >> 6), kp = tid & 63;
      t0[i][kp] = W[(size_t)(hh * 768 + d0 + i) * 64 + kp];
    }
    __syncthreads();
#pragma unroll
    for (int p = 0; p < 16; ++p) {
      int kp = p * 4 + (tid >> 6), i = tid & 63;
      Wcat[(size_t)(sel * 768 + hh * 64 + kp) * 768 + d0 + i] = (f16)t0[i][kp];
    }
  } else if (bid < 432) {  // V@Wo per (head, d-tile), f32 compute
    int idx = bid - 288, hh = idx / 12, dt = idx % 12, d0 = dt * 64;
#pragma unroll
    for (int p = 0; p < 16; ++p) {
      int i = p * 4 + (tid >> 6), m = tid & 63;
      t0[i][m] = Wv[(size_t)(hh * 768 + d0 + i) * 64 + m];
      t1[i * 64 + m] = Wo[(size_t)(hh * 64 + i) * 64 + m];
    }
    __syncthreads();
    int j = tid & 63;
    for (int p = 0; p < 16; ++p) {
      int i = p * 4 + (tid >> 6);
      float a = 0.f;
      for (int m = 0; m < 64; ++m) a += t0[i][m] * t1[m * 64 + j];
      Wcat[(size_t)(1536 + hh * 64 + j) * 768 + d0 + i] = (f16)a;
    }
  } else {  // bvo
    for (int base = 0; base < 768; base += 256) {
      int idx = base + tid, h2 = idx >> 6, j = idx & 63;
      float a = bo[idx];
      for (int m = 0; m < 64; ++m)
        a += bv[h2 * 64 + m] * Wo[(size_t)(h2 * 64 + m) * 64 + j];
      bvo[idx] = a;
    }
  }
}

__global__ __launch_bounds__(256) void x_to_f16(const float* __restrict__ x,
                                                f16* __restrict__ xh) {
  size_t i = (size_t)blockIdx.x * 256 + threadIdx.x;
  float4 v = reinterpret_cast<const float4*>(x)[i];
  f16x4 o;
  o[0] = (f16)v.x; o[1] = (f16)v.y; o[2] = (f16)v.z; o[3] = (f16)v.w;
  reinterpret_cast<f16x4*>(xh)[i] = o;
}

// ---------------------------------------------------------------------------
// Fused Q/K/Vtilde projection: [8192 x 768] @ [768 x 2304] (B^T layout).
// Tile 128x192, 4 waves (2M x 2N), per-wave 64x96 = acc[4][6], 24 MFMA per
// BK=32 step. Grid = 64 x 12 = 768 blocks = EXACTLY 3 blocks/CU resident.
// (R7: this config dropped qkv out of the top-5 — unchanged this round.)
// ---------------------------------------------------------------------------
#define QK_AS (128 * 32)  // f16 elems per A buffer
#define QK_BS (192 * 32)
__global__ __launch_bounds__(256, 3) void qkv_gemm(
    const f16* __restrict__ Xh, const f16* __restrict__ Wcat,
    const float* __restrict__ bq, const float* __restrict__ bk,
    f16* __restrict__ Qo, f16* __restrict__ Ko, f16* __restrict__ Vto) {
  __shared__ __align__(16) f16 SH[2 * QK_AS + 2 * QK_BS];  // 40 KB
  int tid = threadIdx.x, lane = tid & 63, wid = tid >> 6;
  int l16 = lane & 15, g4 = lane >> 4;
  int r0 = blockIdx.x * 128, n0 = blockIdx.y * 192;
  int wm = wid & 1, wn = wid >> 1;
  f32x4 acc[4][6] = {};
  f16x8 ra[2], rb[3];

  auto Abuf = [&](int buf) -> f16* { return SH + buf * QK_AS; };
  auto Bbuf = [&](int buf) -> f16* { return SH + 2 * QK_AS + buf * QK_BS; };

  auto load_ab = [&](int kk) {
#pragma unroll
    for (int ss = 0; ss < 2; ++ss) {
      int s = ss * 256 + tid, row = s >> 2, cs = s & 3;
      int csrc = cs ^ ((row >> 1) & 3);
      ra[ss] = *(const f16x8*)(Xh + (size_t)(r0 + row) * 768 + kk + csrc * 8);
    }
#pragma unroll
    for (int ss = 0; ss < 3; ++ss) {
      int s = ss * 256 + tid, row = s >> 2, cs = s & 3;
      int csrc = cs ^ ((row >> 1) & 3);
      rb[ss] = *(const f16x8*)(Wcat + (size_t)(n0 + row) * 768 + kk + csrc * 8);
    }
  };
  auto store_ab = [&](int buf) {
    f16* A = Abuf(buf);
    f16* B = Bbuf(buf);
#pragma unroll
    for (int ss = 0; ss < 2; ++ss) *(f16x8*)(A + (ss * 256 + tid) * 8) = ra[ss];
#pragma unroll
    for (int ss = 0; ss < 3; ++ss) *(f16x8*)(B + (ss * 256 + tid) * 8) = rb[ss];
  };
  auto compute = [&](int buf) {
    const f16* A = Abuf(buf);
    const f16* B = Bbuf(buf);
    f16x8 af[4], bf[6];
#pragma unroll
    for (int mf = 0; mf < 4; ++mf) {
      int row = wm * 64 + mf * 16 + l16;
      int ch = g4 ^ ((row >> 1) & 3);
      af[mf] = *(const f16x8*)(A + row * 32 + ch * 8);
    }
#pragma unroll
    for (int nf = 0; nf < 6; ++nf) {
      int row = wn * 96 + nf * 16 + l16;
      int ch = g4 ^ ((row >> 1) & 3);
      bf[nf] = *(const f16x8*)(B + row * 32 + ch * 8);
    }
#pragma unroll
    for (int mf = 0; mf < 4; ++mf)
#pragma unroll
      for (int nf = 0; nf < 6; ++nf)
        acc[mf][nf] = __builtin_amdgcn_mfma_f32_16x16x32_f16(af[mf], bf[nf],
                                                             acc[mf][nf], 0, 0, 0);
  };

  load_ab(0);
  store_ab(0);
  __syncthreads();
  int cur = 0;
  for (int kk = 0; kk < 768; kk += 32) {
    bool more = kk + 32 < 768;
    if (more) load_ab(kk + 32);  // global->reg, overlaps MFMAs below
    compute(cur);
    if (more) {
      store_ab(cur ^ 1);  // vmcnt wait lands here, not at a dead barrier
      __syncthreads();
      cur ^= 1;
    }
  }

  int sel = n0 / 768;   // uniform per block (192*4 = 768)
  int nrem = n0 % 768;  // 0,192,384,576
  __syncthreads();      // all ds_reads of A/B done before SH reuse
  if (sel < 2) {
    // Q/K: bias (+Q scale), LDS transpose [64][208], coalesced f16x8 rows
    const float* bp = sel == 0 ? bq : bk;
    float scl = sel == 0 ? QSCALE : 1.f;
    f16* dst = sel == 0 ? Qo : Ko;
#pragma unroll
    for (int rh = 0; rh < 2; ++rh) {
      if (wm == rh) {
#pragma unroll
        for (int nf = 0; nf < 6; ++nf) {
          int c = wn * 96 + nf * 16 + l16;
          float bia = bp[nrem + c];
#pragma unroll
          for (int mf = 0; mf < 4; ++mf)
#pragma unroll
            for (int r = 0; r < 4; ++r)
              SH[(mf * 16 + g4 * 4 + r) * 208 + c] =
                  (f16)((acc[mf][nf][r] + bia) * scl);
        }
      }
      __syncthreads();
#pragma unroll
      for (int p = 0; p < 6; ++p) {
        int cl = p * 256 + tid;           // 64 rows x 24 chunks
        int lr = cl / 24, ch = cl % 24;
        int grow = r0 + rh * 64 + lr;
        int b = grow >> 10, s = grow & 1023;
        int col = nrem + ch * 8;
        int hh = col >> 6, kp = col & 63;
        f16x8 v = *(const f16x8*)(SH + lr * 208 + ch * 8);
        *(f16x8*)(dst + ((size_t)(b * 12 + hh) * 1024 + s) * 64 + kp) = v;
      }
      __syncthreads();
    }
  } else {
    // Vtilde^T: LDS transpose [192][72] (col-major), coalesced f16x8 along s
#pragma unroll
    for (int rh = 0; rh < 2; ++rh) {
      if (wm == rh) {
#pragma unroll
        for (int nf = 0; nf < 6; ++nf) {
          int c = wn * 96 + nf * 16 + l16;
#pragma unroll
          for (int mf = 0; mf < 4; ++mf)
#pragma unroll
            for (int r = 0; r < 4; ++r)
              SH[c * 72 + mf * 16 + g4 * 4 + r] = (f16)acc[mf][nf][r];
        }
      }
      __syncthreads();
      int grow0 = r0 + rh * 64;
      int b = grow0 >> 10, s0 = grow0 & 1023;
#pragma unroll
      for (int p = 0; p < 6; ++p) {
        int cl = p * 256 + tid;  // 192 cols x 8 chunks
        int c = cl >> 3, ch = cl & 7;
        int col = nrem + c;
        int hh = col >> 6, kp = col & 63;
        f16x8 v = *(const f16x8*)(SH + c * 72 + ch * 8);
        *(f16x8*)(Vto + ((size_t)(b * 12 + hh) * 64 + kp) * 1024 + s0 + ch * 8) = v;
      }
      __syncthreads();
    }
  }
}

// ---------------------------------------------------------------------------
// Flash attention (R2 structure), swapped-operand 32x32x16 MFMA, in-register
// softmax (T12), defer-max (T13), Wo folded into Vtilde.
// R8 change (T1): 1-D grid of 768 with lin = qb*96 + hb decode, so all 8
// q-blocks of one (b,h) satisfy lin%8 == hb%8 -> SAME XCD -> their shared
// 256 KB K/V pair stays in that XCD's 4 MB L2 (12 pairs x 256 KB = 3 MB/XCD).
// Also equalizes load: 96 blocks/XCD = exactly 3 blocks/CU.
// ---------------------------------------------------------------------------
struct SMemKV { f16 K[2][64 * 64]; f16 V[2][64 * 64]; };
union SMemU { SMemKV kv; float O[4 * 32 * 68]; };

__global__ __launch_bounds__(256, 3) void attn_fused(
    const f16* __restrict__ Qg, const f16* __restrict__ Kg,
    const f16* __restrict__ Vt, const float* __restrict__ bvo,
    f16* __restrict__ XhOut, float* __restrict__ Fout, int last) {
  __shared__ __align__(16) SMemU sm;
  int tid = threadIdx.x, lane = tid & 63, wid = tid >> 6;
  int l32 = lane & 31, hi = lane >> 5;
  int lin = blockIdx.x;
  int qb = lin / 96;       // 0..7
  int hb = lin % 96;       // lin%8 == hb%8 -> XCD owner of this (b,h)
  int hh = hb % 12, bb = hb / 12;
  int q0 = qb * 128;
  size_t bh = (size_t)bb * 12 + hh;
  const f16* Qp = Qg + bh * (1024 * 64);
  const f16* Kp = Kg + bh * (1024 * 64);
  const f16* Vp = Vt + bh * (64 * 1024);

  f16x8 qf[4];
#pragma unroll
  for (int kf = 0; kf < 4; ++kf)
    qf[kf] = *(const f16x8*)(Qp + (size_t)(q0 + wid * 32 + l32) * 64 + kf * 16 + hi * 8);

  f16x8 rk[2], rv[2];
  auto kv_load = [&](int t0) {
#pragma unroll
    for (int ss = 0; ss < 2; ++ss) {
      int cl = ss * 256 + tid, r = cl >> 3, c = cl & 7;
      rk[ss] = *(const f16x8*)(Kp + (size_t)(t0 + r) * 64 + c * 8);
      rv[ss] = *(const f16x8*)(Vp + (size_t)r * 1024 + t0 + c * 8);
    }
  };
  auto kv_store = [&](int buf) {
#pragma unroll
    for (int ss = 0; ss < 2; ++ss) {
      int cl = ss * 256 + tid, r = cl >> 3, c = cl & 7;
      int cs = c ^ (r & 7);
      *(f16x8*)(sm.kv.K[buf] + r * 64 + cs * 8) = rk[ss];
      *(f16x8*)(sm.kv.V[buf] + r * 64 + cs * 8) = rv[ss];
    }
  };

  f32x16 oacc0 = {}, oacc1 = {};
  float m = -1e30f, lsum = 0.f;

  kv_load(0);
  kv_store(0);
  __syncthreads();
  int cur = 0;
  for (int t = 0; t < 16; ++t) {
    bool more = t < 15;
    if (more) kv_load((t + 1) * 64);
    const f16* Kc = sm.kv.K[cur];
    const f16* Vc = sm.kv.V[cur];
    f32x16 sc0 = {}, sc1 = {};
#pragma unroll
    for (int kf = 0; kf < 4; ++kf) {
      int ch = (2 * kf + hi) ^ (l32 & 7);
      f16x8 k0 = *(const f16x8*)(Kc + l32 * 64 + ch * 8);
      sc0 = __builtin_amdgcn_mfma_f32_32x32x16_f16(k0, qf[kf], sc0, 0, 0, 0);
      f16x8 k1 = *(const f16x8*)(Kc + (32 + l32) * 64 + ch * 8);
      sc1 = __builtin_amdgcn_mfma_f32_32x32x16_f16(k1, qf[kf], sc1, 0, 0, 0);
    }
    float mx[16];
#pragma unroll
    for (int j = 0; j < 16; ++j) mx[j] = fmaxf(sc0[j], sc1[j]);
#pragma unroll
    for (int s = 8; s >= 1; s >>= 1)
#pragma unroll
      for (int j = 0; j < 8; ++j)
        if (j < s) mx[j] = fmaxf(mx[j], mx[j + s]);
    float pmax = fmaxf(mx[0], __shfl_xor(mx[0], 32));
    if (__any(pmax > m + 8.f)) {
      float mn = fmaxf(m, pmax);
      float c = fexp2(m - mn);
      lsum *= c;
#pragma unroll
      for (int j = 0; j < 16; ++j) { oacc0[j] *= c; oacc1[j] *= c; }
      m = mn;
    }
    unsigned w[8][2];
    float qs[8];
#pragma unroll
    for (int qd = 0; qd < 8; ++qd) {
      float a0, a1, a2, a3;
      if (qd < 4) {
        a0 = fexp2(sc0[qd * 4 + 0] - m); a1 = fexp2(sc0[qd * 4 + 1] - m);
        a2 = fexp2(sc0[qd * 4 + 2] - m); a3 = fexp2(sc0[qd * 4 + 3] - m);
      } else {
        a0 = fexp2(sc1[(qd - 4) * 4 + 0] - m); a1 = fexp2(sc1[(qd - 4) * 4 + 1] - m);
        a2 = fexp2(sc1[(qd - 4) * 4 + 2] - m); a3 = fexp2(sc1[(qd - 4) * 4 + 3] - m);
      }
      qs[qd] = (a0 + a1) + (a2 + a3);
      w[qd][0] = __builtin_bit_cast(unsigned, __builtin_amdgcn_cvt_pkrtz(a0, a1));
      w[qd][1] = __builtin_bit_cast(unsigned, __builtin_amdgcn_cvt_pkrtz(a2, a3));
    }
    lsum += ((qs[0] + qs[1]) + (qs[2] + qs[3])) + ((qs[4] + qs[5]) + (qs[6] + qs[7]));
#pragma unroll
    for (int kf = 0; kf < 4; ++kf) {
      int QB = (kf >> 1) * 4 + 2 * (kf & 1);
      unsigned lo0, lo1, hi0, hi1;
      {
        unsigned s0 = hi ? w[QB][0] : w[QB + 1][0];
        unsigned s1 = hi ? w[QB][1] : w[QB + 1][1];
        unsigned r0 = __shfl_xor(s0, 32);
        unsigned r1 = __shfl_xor(s1, 32);
        lo0 = hi ? r0 : w[QB][0];
        lo1 = hi ? r1 : w[QB][1];
        hi0 = hi ? w[QB + 1][0] : r0;
        hi1 = hi ? w[QB + 1][1] : r1;
      }
      u32x4 pw = {lo0, lo1, hi0, hi1};
      f16x8 pf = __builtin_bit_cast(f16x8, pw);
      int ch = (2 * kf + hi) ^ (l32 & 7);
      f16x8 v0 = *(const f16x8*)(Vc + l32 * 64 + ch * 8);
      oacc0 = __builtin_amdgcn_mfma_f32_32x32x16_f16(v0, pf, oacc0, 0, 0, 0);
      f16x8 v1 = *(const f16x8*)(Vc + (32 + l32) * 64 + ch * 8);
      oacc1 = __builtin_amdgcn_mfma_f32_32x32x16_f16(v1, pf, oacc1, 0, 0, 0);
    }
    if (more) {
      kv_store(cur ^ 1);
      __syncthreads();
      cur ^= 1;
    }
  }
  float lt = lsum + __shfl_xor(lsum, 32);
  float inv = 1.f / lt;
  __syncthreads();
  float* Ow = sm.O + wid * (32 * 68) + l32 * 68;
#pragma unroll
  for (int dt = 0; dt < 2; ++dt) {
#pragma unroll
    for (int g = 0; g < 4; ++g) {
      int d0 = dt * 32 + g * 8 + hi * 4;
      f32x4 st;
      if (dt == 0) {
        st[0] = oacc0[g * 4 + 0] * inv; st[1] = oacc0[g * 4 + 1] * inv;
        st[2] = oacc0[g * 4 + 2] * inv; st[3] = oacc0[g * 4 + 3] * inv;
      } else {
        st[0] = oacc1[g * 4 + 0] * inv; st[1] = oacc1[g * 4 + 1] * inv;
        st[2] = oacc1[g * 4 + 2] * inv; st[3] = oacc1[g * 4 + 3] * inv;
      }
      *(f32x4*)(Ow + d0) = st;
    }
  }
  __syncthreads();
  int base_q = bb * 1024 + q0;
#pragma unroll
  for (int p = 0; p < 8; ++p) {
    int cl = p * 256 + tid;
    int row = cl >> 4, c = cl & 15;
    f32x4 v = *(const f32x4*)(sm.O + (row >> 5) * (32 * 68) + (row & 31) * 68 + c * 4);
    float4 bv4 = *(const float4*)(bvo + hh * 64 + c * 4);
    v[0] += bv4.x; v[1] += bv4.y; v[2] += bv4.z; v[3] += bv4.w;
    size_t off = (size_t)(base_q + row) * 768 + hh * 64 + c * 4;
    if (last) {
      *(f32x4*)(Fout + off) = v;
    } else {
      f16x4 hq;
      hq[0] = (f16)v[0]; hq[1] = (f16)v[1]; hq[2] = (f16)v[2]; hq[3] = (f16)v[3];
      *(f16x4*)(XhOut + off) = hq;
    }
  }
}

// ---------------------------------------------------------------------------
extern "C" void kernel_launch(void* const* d_in, const int* in_sizes, int n_in,
                              void* d_out, int out_size, void* d_ws,
                              size_t ws_size, hipStream_t stream) {
  const float* x = (const float*)d_in[0];
  const float* Wq = (const float*)d_in[1];
  const float* bq = (const float*)d_in[2];
  const float* Wk = (const float*)d_in[3];
  const float* bk = (const float*)d_in[4];
  const float* Wv = (const float*)d_in[5];
  const float* bv = (const float*)d_in[6];
  const float* Wo = (const float*)d_in[7];
  const float* bo = (const float*)d_in[8];
  float* out = (float*)d_out;

  char* ws = (char*)d_ws;
  size_t off = 0;
  auto alloc = [&](size_t bytes) -> void* {
    void* p = ws + off;
    off += (bytes + 255) & ~(size_t)255;
    return p;
  };
  f16* Wcat = (f16*)alloc((size_t)NQKV3 * ND * 2);  // 3.54 MB
  float* bvo = (float*)alloc(768 * 4);
  f16* Xh = (f16*)alloc((size_t)NM * ND * 2);   // 12.6 MB
  f16* Qb = (f16*)alloc((size_t)NM * ND * 2);   // B*H*S*HD
  f16* Kb = (f16*)alloc((size_t)NM * ND * 2);
  f16* Vtb = (f16*)alloc((size_t)NM * ND * 2);

  prep_weights<<<433, 256, 0, stream>>>(Wq, Wk, Wv, Wo, bv, bo, Wcat, bvo);
  x_to_f16<<<(NM * ND / 4) / 256, 256, 0, stream>>>(x, Xh);
  for (int l = 0; l < NLAYERS; ++l) {
    qkv_gemm<<<dim3(NM / 128, NQKV3 / 192), 256, 0, stream>>>(
        Xh, Wcat, bq, bk, Qb, Kb, Vtb);
    attn_fused<<<768, 256, 0, stream>>>(
        Qb, Kb, Vtb, bvo, Xh, out, l == NLAYERS - 1);
  }
}

// Round 10
// 942.985 us; speedup vs baseline: 1.3407x; 1.0113x over previous
//
#include <hip/hip_runtime.h>

#define NB 8
#define NS 1024
#define ND 768
#define NH 12
#define NHD 64
#define NLAYERS 12
#define NM (NB * NS)   // 8192 rows
#define NQKV3 (3 * ND) // 2304 output cols of fused QKV GEMM
#define QSCALE 0.1803368802f  // (1/8) * log2(e): softmax runs in exp2 domain

typedef _Float16 f16;
typedef _Float16 f16x8 __attribute__((ext_vector_type(8)));
typedef _Float16 f16x4 __attribute__((ext_vector_type(4)));
typedef _Float16 f16x2 __attribute__((ext_vector_type(2)));
typedef float f32x4 __attribute__((ext_vector_type(4)));
typedef float f32x16 __attribute__((ext_vector_type(16)));
typedef unsigned int u32x4 __attribute__((ext_vector_type(4)));

__device__ inline float fexp2(float x) {
  float r;
  asm("v_exp_f32 %0, %1" : "=v"(r) : "v"(x));
  return r;
}

// async global->LDS DMA, 16B per lane; LDS dest = wave-uniform base + lane*16
__device__ __forceinline__ void gload16(const void* g, void* l) {
  __builtin_amdgcn_global_load_lds(
      (const __attribute__((address_space(1))) void*)g,
      (__attribute__((address_space(3))) void*)l, 16, 0, 0);
}

// ---------------------------------------------------------------------------
// One-time weight prep.
//  Wcat[n][d] (f16, B^T layout), n = sel*768 + h*64 + kp:
//    sel 0: Wq[h][d][kp]   sel 1: Wk[h][d][kp]   sel 2: (Wv@Wo)[h][d][kp]
//  bvo[h*64+j] = sum_m bv[h][m]*Wo[h][m][j] + bo[h][j]
// ---------------------------------------------------------------------------
__global__ __launch_bounds__(256) void prep_weights(
    const float* __restrict__ Wq, const float* __restrict__ Wk,
    const float* __restrict__ Wv, const float* __restrict__ Wo,
    const float* __restrict__ bv, const float* __restrict__ bo,
    f16* __restrict__ Wcat, float* __restrict__ bvo) {
  __shared__ float t0[64][65];
  __shared__ float t1[64 * 64];
  int bid = blockIdx.x, tid = threadIdx.x;
  if (bid < 288) {  // Q,K transposes
    int dt = bid % 12, hh = (bid / 12) % 12, sel = bid / 144;
    const float* W = sel == 0 ? Wq : Wk;
    int d0 = dt * 64;
#pragma unroll
    for (int p = 0; p < 16; ++p) {
      int i = p * 4 + (tid >> 6), kp = tid & 63;
      t0[i][kp] = W[(size_t)(hh * 768 + d0 + i) * 64 + kp];
    }
    __syncthreads();
#pragma unroll
    for (int p = 0; p < 16; ++p) {
      int kp = p * 4 + (tid >> 6), i = tid & 63;
      Wcat[(size_t)(sel * 768 + hh * 64 + kp) * 768 + d0 + i] = (f16)t0[i][kp];
    }
  } else if (bid < 432) {  // V@Wo per (head, d-tile), f32 compute
    int idx = bid - 288, hh = idx / 12, dt = idx % 12, d0 = dt * 64;
#pragma unroll
    for (int p = 0; p < 16; ++p) {
      int i = p * 4 + (tid >> 6), m = tid & 63;
      t0[i][m] = Wv[(size_t)(hh * 768 + d0 + i) * 64 + m];
      t1[i * 64 + m] = Wo[(size_t)(hh * 64 + i) * 64 + m];
    }
    __syncthreads();
    int j = tid & 63;
    for (int p = 0; p < 16; ++p) {
      int i = p * 4 + (tid >> 6);
      float a = 0.f;
      for (int m = 0; m < 64; ++m) a += t0[i][m] * t1[m * 64 + j];
      Wcat[(size_t)(1536 + hh * 64 + j) * 768 + d0 + i] = (f16)a;
    }
  } else {  // bvo
    for (int base = 0; base < 768; base += 256) {
      int idx = base + tid, h2 = idx >> 6, j = idx & 63;
      float a = bo[idx];
      for (int m = 0; m < 64; ++m)
        a += bv[h2 * 64 + m] * Wo[(size_t)(h2 * 64 + m) * 64 + j];
      bvo[idx] = a;
    }
  }
}

__global__ __launch_bounds__(256) void x_to_f16(const float* __restrict__ x,
                                                f16* __restrict__ xh) {
  size_t i = (size_t)blockIdx.x * 256 + threadIdx.x;
  float4 v = reinterpret_cast<const float4*>(x)[i];
  f16x4 o;
  o[0] = (f16)v.x; o[1] = (f16)v.y; o[2] = (f16)v.z; o[3] = (f16)v.w;
  reinterpret_cast<f16x4*>(xh)[i] = o;
}

// ---------------------------------------------------------------------------
// Fused Q/K/Vtilde projection: [8192 x 768] @ [768 x 2304] (B^T layout).
// Tile 128x192, 4 waves (2M x 2N), per-wave 64x96 = acc[4][6], 24 MFMA per
// BK=32 step. Grid = 64 x 12 = 768 blocks = EXACTLY 3 blocks/CU, one round.
// R9: staging via global_load_lds width=16 (m97/m151/m193 lever, first clean
// test now that the scatter epilogue is gone). LDS dest LINEAR (HW req);
// conflict-free ds_reads preserved by pre-swizzling the GLOBAL source column
// (read-side XOR cancels). __syncthreads drains vmcnt -> 1 barrier/step.
// Epilogues via LDS transpose -> coalesced f16x8 stores (R7, kept).
// ---------------------------------------------------------------------------
#define QK_AS (128 * 32)  // f16 elems per A buffer (8 KB)
#define QK_BS (192 * 32)  // f16 elems per B buffer (12 KB)
__global__ __launch_bounds__(256, 3) void qkv_gemm(
    const f16* __restrict__ Xh, const f16* __restrict__ Wcat,
    const float* __restrict__ bq, const float* __restrict__ bk,
    f16* __restrict__ Qo, f16* __restrict__ Ko, f16* __restrict__ Vto) {
  __shared__ __align__(16) f16 SH[2 * QK_AS + 2 * QK_BS];  // 40 KB
  int tid = threadIdx.x, lane = tid & 63, wid = tid >> 6;
  int l16 = lane & 15, g4 = lane >> 4;
  int r0 = blockIdx.x * 128, n0 = blockIdx.y * 192;
  int wm = wid & 1, wn = wid >> 1;
  f32x4 acc[4][6] = {};

  // per-thread staging geometry: slot s = ss*256+tid -> row = s>>2, cs = s&3;
  // LDS gets linear slot*16 bytes; global source col chunk = cs ^ ((row>>1)&3)
  const f16* gA[2];
  const f16* gB[3];
  int la[2], lb[3];
#pragma unroll
  for (int ss = 0; ss < 2; ++ss) {
    int s = ss * 256 + tid, row = s >> 2, cs = s & 3;
    int csrc = cs ^ ((row >> 1) & 3);
    gA[ss] = Xh + (size_t)(r0 + row) * 768 + csrc * 8;
    la[ss] = s * 16;
  }
#pragma unroll
  for (int ss = 0; ss < 3; ++ss) {
    int s = ss * 256 + tid, row = s >> 2, cs = s & 3;
    int csrc = cs ^ ((row >> 1) & 3);
    gB[ss] = Wcat + (size_t)(n0 + row) * 768 + csrc * 8;
    lb[ss] = s * 16;
  }
  auto stage = [&](int buf, int kk) {
    char* A = (char*)(SH + buf * QK_AS);
    char* B = (char*)(SH + 2 * QK_AS + buf * QK_BS);
#pragma unroll
    for (int ss = 0; ss < 2; ++ss) gload16(gA[ss] + kk, A + la[ss]);
#pragma unroll
    for (int ss = 0; ss < 3; ++ss) gload16(gB[ss] + kk, B + lb[ss]);
  };
  auto compute = [&](int buf) {
    const f16* A = SH + buf * QK_AS;
    const f16* B = SH + 2 * QK_AS + buf * QK_BS;
    f16x8 af[4], bf[6];
#pragma unroll
    for (int mf = 0; mf < 4; ++mf) {
      int row = wm * 64 + mf * 16 + l16;
      int ch = g4 ^ ((row >> 1) & 3);
      af[mf] = *(const f16x8*)(A + row * 32 + ch * 8);
    }
#pragma unroll
    for (int nf = 0; nf < 6; ++nf) {
      int row = wn * 96 + nf * 16 + l16;
      int ch = g4 ^ ((row >> 1) & 3);
      bf[nf] = *(const f16x8*)(B + row * 32 + ch * 8);
    }
#pragma unroll
    for (int mf = 0; mf < 4; ++mf)
#pragma unroll
      for (int nf = 0; nf < 6; ++nf)
        acc[mf][nf] = __builtin_amdgcn_mfma_f32_16x16x32_f16(af[mf], bf[nf],
                                                             acc[mf][nf], 0, 0, 0);
  };

  stage(0, 0);
  __syncthreads();  // drains vmcnt -> buf0 ready
  int cur = 0;
  for (int kk = 0; kk < 768; kk += 32) {
    bool more = kk + 32 < 768;
    if (more) stage(cur ^ 1, kk + 32);  // DMA in flight across the MFMAs
    compute(cur);
    if (more) {
      __syncthreads();  // drains vmcnt -> next buf landed; readers done
      cur ^= 1;
    }
  }

  int sel = n0 / 768;   // uniform per block (192*4 = 768)
  int nrem = n0 % 768;  // 0,192,384,576
  __syncthreads();      // all ds_reads of A/B done before SH reuse
  if (sel < 2) {
    // Q/K: bias (+Q scale), LDS transpose [64][208], coalesced f16x8 rows
    const float* bp = sel == 0 ? bq : bk;
    float scl = sel == 0 ? QSCALE : 1.f;
    f16* dst = sel == 0 ? Qo : Ko;
#pragma unroll
    for (int rh = 0; rh < 2; ++rh) {
      if (wm == rh) {
#pragma unroll
        for (int nf = 0; nf < 6; ++nf) {
          int c = wn * 96 + nf * 16 + l16;
          float bia = bp[nrem + c];
#pragma unroll
          for (int mf = 0; mf < 4; ++mf)
#pragma unroll
            for (int r = 0; r < 4; ++r)
              SH[(mf * 16 + g4 * 4 + r) * 208 + c] =
                  (f16)((acc[mf][nf][r] + bia) * scl);
        }
      }
      __syncthreads();
#pragma unroll
      for (int p = 0; p < 6; ++p) {
        int cl = p * 256 + tid;           // 64 rows x 24 chunks
        int lr = cl / 24, ch = cl % 24;
        int grow = r0 + rh * 64 + lr;
        int b = grow >> 10, s = grow & 1023;
        int col = nrem + ch * 8;
        int hh = col >> 6, kp = col & 63;
        f16x8 v = *(const f16x8*)(SH + lr * 208 + ch * 8);
        *(f16x8*)(dst + ((size_t)(b * 12 + hh) * 1024 + s) * 64 + kp) = v;
      }
      __syncthreads();
    }
  } else {
    // Vtilde^T: LDS transpose [192][72] (col-major), coalesced f16x8 along s
#pragma unroll
    for (int rh = 0; rh < 2; ++rh) {
      if (wm == rh) {
#pragma unroll
        for (int nf = 0; nf < 6; ++nf) {
          int c = wn * 96 + nf * 16 + l16;
#pragma unroll
          for (int mf = 0; mf < 4; ++mf)
#pragma unroll
            for (int r = 0; r < 4; ++r)
              SH[c * 72 + mf * 16 + g4 * 4 + r] = (f16)acc[mf][nf][r];
        }
      }
      __syncthreads();
      int grow0 = r0 + rh * 64;
      int b = grow0 >> 10, s0 = grow0 & 1023;
#pragma unroll
      for (int p = 0; p < 6; ++p) {
        int cl = p * 256 + tid;  // 192 cols x 8 chunks
        int c = cl >> 3, ch = cl & 7;
        int col = nrem + c;
        int hh = col >> 6, kp = col & 63;
        f16x8 v = *(const f16x8*)(SH + c * 72 + ch * 8);
        *(f16x8*)(Vto + ((size_t)(b * 12 + hh) * 64 + kp) * 1024 + s0 + ch * 8) = v;
      }
      __syncthreads();
    }
  }
}

// ---------------------------------------------------------------------------
// Flash attention (R2 structure + R8 T1 grid remap), swapped-operand 32x32x16
// MFMA, in-register softmax (T12), defer-max (T13), Wo folded into Vtilde.
// 1-D grid 768, lin = qb*96 + hb: all 8 q-blocks of a (b,h) share an XCD ->
// K/V stays in that XCD's L2 (12 pairs x 256 KB = 3 MB/XCD). R8: 55 -> ~32 us.
// ---------------------------------------------------------------------------
struct SMemKV { f16 K[2][64 * 64]; f16 V[2][64 * 64]; };
union SMemU { SMemKV kv; float O[4 * 32 * 68]; };

__global__ __launch_bounds__(256, 3) void attn_fused(
    const f16* __restrict__ Qg, const f16* __restrict__ Kg,
    const f16* __restrict__ Vt, const float* __restrict__ bvo,
    f16* __restrict__ XhOut, float* __restrict__ Fout, int last) {
  __shared__ __align__(16) SMemU sm;
  int tid = threadIdx.x, lane = tid & 63, wid = tid >> 6;
  int l32 = lane & 31, hi = lane >> 5;
  int lin = blockIdx.x;
  int qb = lin / 96;       // 0..7
  int hb = lin % 96;       // lin%8 == hb%8 -> XCD owner of this (b,h)
  int hh = hb % 12, bb = hb / 12;
  int q0 = qb * 128;
  size_t bh = (size_t)bb * 12 + hh;
  const f16* Qp = Qg + bh * (1024 * 64);
  const f16* Kp = Kg + bh * (1024 * 64);
  const f16* Vp = Vt + bh * (64 * 1024);

  f16x8 qf[4];
#pragma unroll
  for (int kf = 0; kf < 4; ++kf)
    qf[kf] = *(const f16x8*)(Qp + (size_t)(q0 + wid * 32 + l32) * 64 + kf * 16 + hi * 8);

  f16x8 rk[2], rv[2];
  auto kv_load = [&](int t0) {
#pragma unroll
    for (int ss = 0; ss < 2; ++ss) {
      int cl = ss * 256 + tid, r = cl >> 3, c = cl & 7;
      rk[ss] = *(const f16x8*)(Kp + (size_t)(t0 + r) * 64 + c * 8);
      rv[ss] = *(const f16x8*)(Vp + (size_t)r * 1024 + t0 + c * 8);
    }
  };
  auto kv_store = [&](int buf) {
#pragma unroll
    for (int ss = 0; ss < 2; ++ss) {
      int cl = ss * 256 + tid, r = cl >> 3, c = cl & 7;
      int cs = c ^ (r & 7);
      *(f16x8*)(sm.kv.K[buf] + r * 64 + cs * 8) = rk[ss];
      *(f16x8*)(sm.kv.V[buf] + r * 64 + cs * 8) = rv[ss];
    }
  };

  f32x16 oacc0 = {}, oacc1 = {};
  float m = -1e30f, lsum = 0.f;

  kv_load(0);
  kv_store(0);
  __syncthreads();
  int cur = 0;
  for (int t = 0; t < 16; ++t) {
    bool more = t < 15;
    if (more) kv_load((t + 1) * 64);
    const f16* Kc = sm.kv.K[cur];
    const f16* Vc = sm.kv.V[cur];
    f32x16 sc0 = {}, sc1 = {};
#pragma unroll
    for (int kf = 0; kf < 4; ++kf) {
      int ch = (2 * kf + hi) ^ (l32 & 7);
      f16x8 k0 = *(const f16x8*)(Kc + l32 * 64 + ch * 8);
      sc0 = __builtin_amdgcn_mfma_f32_32x32x16_f16(k0, qf[kf], sc0, 0, 0, 0);
      f16x8 k1 = *(const f16x8*)(Kc + (32 + l32) * 64 + ch * 8);
      sc1 = __builtin_amdgcn_mfma_f32_32x32x16_f16(k1, qf[kf], sc1, 0, 0, 0);
    }
    float mx[16];
#pragma unroll
    for (int j = 0; j < 16; ++j) mx[j] = fmaxf(sc0[j], sc1[j]);
#pragma unroll
    for (int s = 8; s >= 1; s >>= 1)
#pragma unroll
      for (int j = 0; j < 8; ++j)
        if (j < s) mx[j] = fmaxf(mx[j], mx[j + s]);
    float pmax = fmaxf(mx[0], __shfl_xor(mx[0], 32));
    if (__any(pmax > m + 8.f)) {
      float mn = fmaxf(m, pmax);
      float c = fexp2(m - mn);
      lsum *= c;
#pragma unroll
      for (int j = 0; j < 16; ++j) { oacc0[j] *= c; oacc1[j] *= c; }
      m = mn;
    }
    unsigned w[8][2];
    float qs[8];
#pragma unroll
    for (int qd = 0; qd < 8; ++qd) {
      float a0, a1, a2, a3;
      if (qd < 4) {
        a0 = fexp2(sc0[qd * 4 + 0] - m); a1 = fexp2(sc0[qd * 4 + 1] - m);
        a2 = fexp2(sc0[qd * 4 + 2] - m); a3 = fexp2(sc0[qd * 4 + 3] - m);
      } else {
        a0 = fexp2(sc1[(qd - 4) * 4 + 0] - m); a1 = fexp2(sc1[(qd - 4) * 4 + 1] - m);
        a2 = fexp2(sc1[(qd - 4) * 4 + 2] - m); a3 = fexp2(sc1[(qd - 4) * 4 + 3] - m);
      }
      qs[qd] = (a0 + a1) + (a2 + a3);
      w[qd][0] = __builtin_bit_cast(unsigned, __builtin_amdgcn_cvt_pkrtz(a0, a1));
      w[qd][1] = __builtin_bit_cast(unsigned, __builtin_amdgcn_cvt_pkrtz(a2, a3));
    }
    lsum += ((qs[0] + qs[1]) + (qs[2] + qs[3])) + ((qs[4] + qs[5]) + (qs[6] + qs[7]));
#pragma unroll
    for (int kf = 0; kf < 4; ++kf) {
      int QB = (kf >> 1) * 4 + 2 * (kf & 1);
      unsigned lo0, lo1, hi0, hi1;
      {
        unsigned s0 = hi ? w[QB][0] : w[QB + 1][0];
        unsigned s1 = hi ? w[QB][1] : w[QB + 1][1];
        unsigned r0 = __shfl_xor(s0, 32);
        unsigned r1 = __shfl_xor(s1, 32);
        lo0 = hi ? r0 : w[QB][0];
        lo1 = hi ? r1 : w[QB][1];
        hi0 = hi ? w[QB + 1][0] : r0;
        hi1 = hi ? w[QB + 1][1] : r1;
      }
      u32x4 pw = {lo0, lo1, hi0, hi1};
      f16x8 pf = __builtin_bit_cast(f16x8, pw);
      int ch = (2 * kf + hi) ^ (l32 & 7);
      f16x8 v0 = *(const f16x8*)(Vc + l32 * 64 + ch * 8);
      oacc0 = __builtin_amdgcn_mfma_f32_32x32x16_f16(v0, pf, oacc0, 0, 0, 0);
      f16x8 v1 = *(const f16x8*)(Vc + (32 + l32) * 64 + ch * 8);
      oacc1 = __builtin_amdgcn_mfma_f32_32x32x16_f16(v1, pf, oacc1, 0, 0, 0);
    }
    if (more) {
      kv_store(cur ^ 1);
      __syncthreads();
      cur ^= 1;
    }
  }
  float lt = lsum + __shfl_xor(lsum, 32);
  float inv = 1.f / lt;
  __syncthreads();
  float* Ow = sm.O + wid * (32 * 68) + l32 * 68;
#pragma unroll
  for (int dt = 0; dt < 2; ++dt) {
#pragma unroll
    for (int g = 0; g < 4; ++g) {
      int d0 = dt * 32 + g * 8 + hi * 4;
      f32x4 st;
      if (dt == 0) {
        st[0] = oacc0[g * 4 + 0] * inv; st[1] = oacc0[g * 4 + 1] * inv;
        st[2] = oacc0[g * 4 + 2] * inv; st[3] = oacc0[g * 4 + 3] * inv;
      } else {
        st[0] = oacc1[g * 4 + 0] * inv; st[1] = oacc1[g * 4 + 1] * inv;
        st[2] = oacc1[g * 4 + 2] * inv; st[3] = oacc1[g * 4 + 3] * inv;
      }
      *(f32x4*)(Ow + d0) = st;
    }
  }
  __syncthreads();
  int base_q = bb * 1024 + q0;
#pragma unroll
  for (int p = 0; p < 8; ++p) {
    int cl = p * 256 + tid;
    int row = cl >> 4, c = cl & 15;
    f32x4 v = *(const f32x4*)(sm.O + (row >> 5) * (32 * 68) + (row & 31) * 68 + c * 4);
    float4 bv4 = *(const float4*)(bvo + hh * 64 + c * 4);
    v[0] += bv4.x; v[1] += bv4.y; v[2] += bv4.z; v[3] += bv4.w;
    size_t off = (size_t)(base_q + row) * 768 + hh * 64 + c * 4;
    if (last) {
      *(f32x4*)(Fout + off) = v;
    } else {
      f16x4 hq;
      hq[0] = (f16)v[0]; hq[1] = (f16)v[1]; hq[2] = (f16)v[2]; hq[3] = (f16)v[3];
      *(f16x4*)(XhOut + off) = hq;
    }
  }
}

// ---------------------------------------------------------------------------
extern "C" void kernel_launch(void* const* d_in, const int* in_sizes, int n_in,
                              void* d_out, int out_size, void* d_ws,
                              size_t ws_size, hipStream_t stream) {
  const float* x = (const float*)d_in[0];
  const float* Wq = (const float*)d_in[1];
  const float* bq = (const float*)d_in[2];
  const float* Wk = (const float*)d_in[3];
  const float* bk = (const float*)d_in[4];
  const float* Wv = (const float*)d_in[5];
  const float* bv = (const float*)d_in[6];
  const float* Wo = (const float*)d_in[7];
  const float* bo = (const float*)d_in[8];
  float* out = (float*)d_out;

  char* ws = (char*)d_ws;
  size_t off = 0;
  auto alloc = [&](size_t bytes) -> void* {
    void* p = ws + off;
    off += (bytes + 255) & ~(size_t)255;
    return p;
  };
  f16* Wcat = (f16*)alloc((size_t)NQKV3 * ND * 2);  // 3.54 MB
  float* bvo = (float*)alloc(768 * 4);
  f16* Xh = (f16*)alloc((size_t)NM * ND * 2);   // 12.6 MB
  f16* Qb = (f16*)alloc((size_t)NM * ND * 2);   // B*H*S*HD
  f16* Kb = (f16*)alloc((size_t)NM * ND * 2);
  f16* Vtb = (f16*)alloc((size_t)NM * ND * 2);

  prep_weights<<<433, 256, 0, stream>>>(Wq, Wk, Wv, Wo, bv, bo, Wcat, bvo);
  x_to_f16<<<(NM * ND / 4) / 256, 256, 0, stream>>>(x, Xh);
  for (int l = 0; l < NLAYERS; ++l) {
    qkv_gemm<<<dim3(NM / 128, NQKV3 / 192), 256, 0, stream>>>(
        Xh, Wcat, bq, bk, Qb, Kb, Vtb);
    attn_fused<<<768, 256, 0, stream>>>(
        Qb, Kb, Vtb, bvo, Xh, out, l == NLAYERS - 1);
  }
}